// Round 1
// baseline (940.606 us; speedup 1.0000x reference)
//
#include <hip/hip_runtime.h>

// ---------------- problem constants ----------------
#define NN 100000      // nodes
#define NE 1600000     // edges (without self loops)
#define DD 128         // feature dim
#define EPSV 1e-5f

#define NBLK_SCAN 391          // ceil(NN/256)
#define RPB 512                // rows per stats block
#define NSB 196                // ceil(NN/RPB)

// ---------------- graph build ----------------
__global__ void k_count(const int* __restrict__ col, int* __restrict__ counts) {
    int e = blockIdx.x * blockDim.x + threadIdx.x;
    if (e < NE) atomicAdd(&counts[col[e]], 1);
}

__global__ void k_dinv(const int* __restrict__ counts, float* __restrict__ dinv) {
    int i = blockIdx.x * blockDim.x + threadIdx.x;
    if (i < NN) dinv[i] = rsqrtf((float)(counts[i] + 1));   // +1 self loop
}

__global__ void k_scanA(const int* __restrict__ counts, int* __restrict__ excl,
                        int* __restrict__ blksum) {
    __shared__ int s[256];
    int tid = threadIdx.x;
    int i = blockIdx.x * 256 + tid;
    int v = (i < NN) ? counts[i] : 0;
    s[tid] = v;
    __syncthreads();
    for (int off = 1; off < 256; off <<= 1) {
        int t = (tid >= off) ? s[tid - off] : 0;
        __syncthreads();
        s[tid] += t;
        __syncthreads();
    }
    if (i < NN) excl[i] = s[tid] - v;          // block-local exclusive
    if (tid == 255) blksum[blockIdx.x] = s[255];
}

__global__ void k_scanB(int* __restrict__ blksum) {
    __shared__ int s[512];
    int tid = threadIdx.x;
    int v = (tid < NBLK_SCAN) ? blksum[tid] : 0;
    s[tid] = v;
    __syncthreads();
    for (int off = 1; off < 512; off <<= 1) {
        int t = (tid >= off) ? s[tid - off] : 0;
        __syncthreads();
        s[tid] += t;
        __syncthreads();
    }
    if (tid < NBLK_SCAN) blksum[tid] = s[tid] - v;   // exclusive over block sums
}

__global__ void k_scanC(int* __restrict__ row_ptr, const int* __restrict__ blksum) {
    int i = blockIdx.x * 256 + threadIdx.x;
    if (i < NN) row_ptr[i] += blksum[blockIdx.x];
    if (i == 0) row_ptr[NN] = NE;
}

__global__ void k_scatter(const int* __restrict__ row, const int* __restrict__ col,
                          const int* __restrict__ row_ptr, int* __restrict__ cursor,
                          const float* __restrict__ dinv,
                          int* __restrict__ csr_src, float* __restrict__ csr_w) {
    int e = blockIdx.x * blockDim.x + threadIdx.x;
    if (e >= NE) return;
    int c = col[e], r = row[e];
    int pos = row_ptr[c] + atomicAdd(&cursor[c], 1);
    csr_src[pos] = r;
    csr_w[pos] = dinv[r] * dinv[c];
}

// ---------------- GEMM: Y[N,128] = T(X)[N,128] @ W[128,128] ----------------
// T(x) = max(0, x*mul[f]+add[f]) if mul != nullptr (fused GraphNorm+ReLU), else x.
// Block: 256 threads, 32 rows. W staged in LDS in two 64-row phases (48KB LDS).
__global__ __launch_bounds__(256, 2)
void k_gemm(const float* __restrict__ X, const float* __restrict__ W,
            float* __restrict__ Y,
            const float* __restrict__ mul, const float* __restrict__ add) {
    __shared__ float sW[64 * 128];   // 32 KB
    __shared__ float sX[32 * 128];   // 16 KB
    const int t = threadIdx.x;
    const int row0 = blockIdx.x * 32;

    // stage X tile (with optional per-feature transform)
    {
        const float4* Xv = (const float4*)(X + (size_t)row0 * DD);
        float4* sXv = (float4*)sX;
        #pragma unroll
        for (int i = 0; i < 4; i++) {
            int idx = t + 256 * i;               // float4 index; 32 f4 per row
            float4 v = Xv[idx];
            if (mul) {
                int f = (idx & 31) * 4;
                float4 m = *(const float4*)(mul + f);
                float4 a = *(const float4*)(add + f);
                v.x = fmaxf(0.f, v.x * m.x + a.x);
                v.y = fmaxf(0.f, v.y * m.y + a.y);
                v.z = fmaxf(0.f, v.z * m.z + a.z);
                v.w = fmaxf(0.f, v.w * m.w + a.w);
            }
            sXv[idx] = v;
        }
    }

    const int cg = t & 31;        // column group: cols 4*cg..
    const int rg = t >> 5;        // row group:    rows 4*rg..
    float acc[4][4] = {};
    const float* xb = sX + rg * 4 * DD;
    const float* wb = sW + cg * 4;

    for (int phase = 0; phase < 2; ++phase) {
        __syncthreads();
        {   // stage 64 rows of W: 8192 floats = 2048 f4, 8 per thread
            const float4* Wv = (const float4*)(W + phase * 64 * DD);
            float4* sWv = (float4*)sW;
            #pragma unroll
            for (int i = 0; i < 8; i++) sWv[t + 256 * i] = Wv[t + 256 * i];
        }
        __syncthreads();
        const int kbase = phase * 64;
        #pragma unroll 4
        for (int k = 0; k < 64; k += 4) {
            float4 xr[4], wr[4];
            #pragma unroll
            for (int r = 0; r < 4; r++) xr[r] = *(const float4*)(xb + r * DD + kbase + k);
            #pragma unroll
            for (int j = 0; j < 4; j++) wr[j] = *(const float4*)(wb + (k + j) * DD);
            #pragma unroll
            for (int r = 0; r < 4; r++) {
                float xv[4] = {xr[r].x, xr[r].y, xr[r].z, xr[r].w};
                #pragma unroll
                for (int j = 0; j < 4; j++) {
                    acc[r][0] = fmaf(xv[j], wr[j].x, acc[r][0]);
                    acc[r][1] = fmaf(xv[j], wr[j].y, acc[r][1]);
                    acc[r][2] = fmaf(xv[j], wr[j].z, acc[r][2]);
                    acc[r][3] = fmaf(xv[j], wr[j].w, acc[r][3]);
                }
            }
        }
    }

    #pragma unroll
    for (int r = 0; r < 4; r++) {
        float4 o = {acc[r][0], acc[r][1], acc[r][2], acc[r][3]};
        *(float4*)(Y + (size_t)(row0 + rg * 4 + r) * DD + cg * 4) = o;
    }
}

// ---------------- aggregation: Y[i] = sum_{e: col=i} h[row_e]*w_e + h[i]*dinv_i^2 + bias ----------------
__global__ __launch_bounds__(128)
void k_agg(const float* __restrict__ H,
           const int* __restrict__ row_ptr, const int* __restrict__ csr_src,
           const float* __restrict__ csr_w, const float* __restrict__ dinv,
           const float* __restrict__ bias, float* __restrict__ Y) {
    const int i = blockIdx.x;
    const int f = threadIdx.x;          // 0..127
    const int lane = threadIdx.x & 63;
    const int p0 = row_ptr[i], p1 = row_ptr[i + 1];
    const float di = dinv[i];
    float acc = H[(size_t)i * DD + f] * di * di;   // self loop
    for (int p = p0; p < p1; p += 64) {
        int navail = p1 - p;
        int srcv = 0; float wv = 0.f;
        if (lane < navail) { srcv = csr_src[p + lane]; wv = csr_w[p + lane]; }
        int m = navail < 64 ? navail : 64;
        for (int j = 0; j < m; j++) {
            int s = __shfl(srcv, j, 64);
            float w = __shfl(wv, j, 64);
            acc = fmaf(H[(size_t)s * DD + f], w, acc);
        }
    }
    Y[(size_t)i * DD + f] = acc + bias[f];
}

// ---------------- GraphNorm stats (two-level, deterministic) ----------------
__global__ __launch_bounds__(256)
void k_stats(const float* __restrict__ X, float* __restrict__ psum, float* __restrict__ psq) {
    __shared__ float ls[128], lq[128];
    int f = threadIdx.x & 127;
    int half = threadIdx.x >> 7;
    int r0 = blockIdx.x * RPB;
    int rend = r0 + RPB; if (rend > NN) rend = NN;
    float s = 0.f, q = 0.f;
    for (int r = r0 + half; r < rend; r += 2) {
        float v = X[(size_t)r * DD + f];
        s += v; q = fmaf(v, v, q);
    }
    if (half) { ls[f] = s; lq[f] = q; }
    __syncthreads();
    if (!half) {
        psum[blockIdx.x * DD + f] = s + ls[f];
        psq[blockIdx.x * DD + f]  = q + lq[f];
    }
}

// mul[f], add[f] such that relu-input y = x*mul + add  ==  w*(x - a*m)*rsqrt(var+eps)+b
__global__ void k_nparams(const float* __restrict__ psum, const float* __restrict__ psq,
                          const float* __restrict__ w, const float* __restrict__ b,
                          const float* __restrict__ a,
                          float* __restrict__ mul, float* __restrict__ add) {
    int f = threadIdx.x;
    float s = 0.f, q = 0.f;
    for (int j = 0; j < NSB; j++) { s += psum[j * DD + f]; q += psq[j * DD + f]; }
    const float invn = 1.0f / (float)NN;
    float m = s * invn;
    float ex2 = q * invn;
    float av = a[f];
    float var = ex2 - m * m * (2.f * av - av * av);   // E[(x-a m)^2]
    float inv = rsqrtf(var + EPSV);
    mul[f] = w[f] * inv;
    add[f] = b[f] - w[f] * inv * av * m;
}

// ---------------- fused MLP head: out = relu(T(X)@W + Wb) @ v1 + b1 ----------------
__global__ __launch_bounds__(256, 2)
void k_mlp(const float* __restrict__ X, const float* __restrict__ W,
           const float* __restrict__ Wb, const float* __restrict__ V1,
           const float* __restrict__ B1,
           const float* __restrict__ mul, const float* __restrict__ add,
           float* __restrict__ out) {
    __shared__ float sW[64 * 128];
    __shared__ float sX[32 * 128];
    const int t = threadIdx.x;
    const int row0 = blockIdx.x * 32;

    {
        const float4* Xv = (const float4*)(X + (size_t)row0 * DD);
        float4* sXv = (float4*)sX;
        #pragma unroll
        for (int i = 0; i < 4; i++) {
            int idx = t + 256 * i;
            float4 v = Xv[idx];
            int f = (idx & 31) * 4;
            float4 m = *(const float4*)(mul + f);
            float4 a = *(const float4*)(add + f);
            v.x = fmaxf(0.f, v.x * m.x + a.x);
            v.y = fmaxf(0.f, v.y * m.y + a.y);
            v.z = fmaxf(0.f, v.z * m.z + a.z);
            v.w = fmaxf(0.f, v.w * m.w + a.w);
            sXv[idx] = v;
        }
    }

    const int cg = t & 31;
    const int rg = t >> 5;
    float acc[4][4] = {};
    const float* xb = sX + rg * 4 * DD;
    const float* wb = sW + cg * 4;

    for (int phase = 0; phase < 2; ++phase) {
        __syncthreads();
        {
            const float4* Wv = (const float4*)(W + phase * 64 * DD);
            float4* sWv = (float4*)sW;
            #pragma unroll
            for (int i = 0; i < 8; i++) sWv[t + 256 * i] = Wv[t + 256 * i];
        }
        __syncthreads();
        const int kbase = phase * 64;
        #pragma unroll 4
        for (int k = 0; k < 64; k += 4) {
            float4 xr[4], wr[4];
            #pragma unroll
            for (int r = 0; r < 4; r++) xr[r] = *(const float4*)(xb + r * DD + kbase + k);
            #pragma unroll
            for (int j = 0; j < 4; j++) wr[j] = *(const float4*)(wb + (k + j) * DD);
            #pragma unroll
            for (int r = 0; r < 4; r++) {
                float xv[4] = {xr[r].x, xr[r].y, xr[r].z, xr[r].w};
                #pragma unroll
                for (int j = 0; j < 4; j++) {
                    acc[r][0] = fmaf(xv[j], wr[j].x, acc[r][0]);
                    acc[r][1] = fmaf(xv[j], wr[j].y, acc[r][1]);
                    acc[r][2] = fmaf(xv[j], wr[j].z, acc[r][2]);
                    acc[r][3] = fmaf(xv[j], wr[j].w, acc[r][3]);
                }
            }
        }
    }

    // epilogue: z = relu(acc + Wb), partial = z . V1, reduce over 32-lane col groups
    float bb[4], l1[4];
    {
        float4 tb = *(const float4*)(Wb + cg * 4);
        bb[0] = tb.x; bb[1] = tb.y; bb[2] = tb.z; bb[3] = tb.w;
        float4 tv = *(const float4*)(V1 + cg * 4);
        l1[0] = tv.x; l1[1] = tv.y; l1[2] = tv.z; l1[3] = tv.w;
    }
    float part[4];
    #pragma unroll
    for (int r = 0; r < 4; r++) {
        float p = 0.f;
        #pragma unroll
        for (int c = 0; c < 4; c++) {
            float z = fmaxf(0.f, acc[r][c] + bb[c]);
            p = fmaf(z, l1[c], p);
        }
        #pragma unroll
        for (int off = 16; off > 0; off >>= 1) p += __shfl_xor(p, off, 64);
        part[r] = p;
    }
    if (cg == 0) {
        float ob = B1[0];
        #pragma unroll
        for (int r = 0; r < 4; r++) out[row0 + rg * 4 + r] = part[r] + ob;
    }
}

// ---------------- launch ----------------
static inline char* wsalloc(char*& p, size_t bytes) {
    char* r = p;
    p += (bytes + 255) & ~(size_t)255;
    return r;
}

extern "C" void kernel_launch(void* const* d_in, const int* in_sizes, int n_in,
                              void* d_out, int out_size, void* d_ws, size_t ws_size,
                              hipStream_t stream) {
    const float* x     = (const float*)d_in[0];
    const int*   ei    = (const int*)d_in[1];
    const int*   row   = ei;
    const int*   col   = ei + NE;
    const float* W0    = (const float*)d_in[2];
    const float* b0    = (const float*)d_in[3];
    const float* W1    = (const float*)d_in[4];
    const float* b1    = (const float*)d_in[5];
    const float* gn0w  = (const float*)d_in[6];
    const float* gn0b  = (const float*)d_in[7];
    const float* gn0a  = (const float*)d_in[8];
    const float* gn1w  = (const float*)d_in[9];
    const float* gn1b  = (const float*)d_in[10];
    const float* gn1a  = (const float*)d_in[11];
    const float* lin0w = (const float*)d_in[12];
    const float* lin0b = (const float*)d_in[13];
    const float* lin1w = (const float*)d_in[14];
    const float* lin1b = (const float*)d_in[15];
    float* out = (float*)d_out;

    char* p = (char*)d_ws;
    float* bufA   = (float*)wsalloc(p, (size_t)NN * DD * 4);
    float* bufB   = (float*)wsalloc(p, (size_t)NN * DD * 4);
    int*   csr_src= (int*)  wsalloc(p, (size_t)NE * 4);
    float* csr_w  = (float*)wsalloc(p, (size_t)NE * 4);
    int*   counts = (int*)  wsalloc(p, (size_t)NN * 4);
    int*   row_ptr= (int*)  wsalloc(p, (size_t)(NN + 1) * 4);
    int*   cursor = (int*)  wsalloc(p, (size_t)NN * 4);
    float* dinv   = (float*)wsalloc(p, (size_t)NN * 4);
    int*   blksum = (int*)  wsalloc(p, 512 * 4);
    float* psum   = (float*)wsalloc(p, (size_t)NSB * DD * 4);
    float* psq    = (float*)wsalloc(p, (size_t)NSB * DD * 4);
    float* mulv   = (float*)wsalloc(p, DD * 4);
    float* addv   = (float*)wsalloc(p, DD * 4);

    hipMemsetAsync(counts, 0, (size_t)NN * 4, stream);
    hipMemsetAsync(cursor, 0, (size_t)NN * 4, stream);

    // graph build
    k_count  <<<(NE + 255) / 256, 256, 0, stream>>>(col, counts);
    k_dinv   <<<(NN + 255) / 256, 256, 0, stream>>>(counts, dinv);
    k_scanA  <<<NBLK_SCAN, 256, 0, stream>>>(counts, row_ptr, blksum);
    k_scanB  <<<1, 512, 0, stream>>>(blksum);
    k_scanC  <<<NBLK_SCAN, 256, 0, stream>>>(row_ptr, blksum);
    k_scatter<<<(NE + 255) / 256, 256, 0, stream>>>(row, col, row_ptr, cursor, dinv,
                                                    csr_src, csr_w);

    // stage 1: h = x@W0 ; agg+bias ; stats
    k_gemm <<<NN / 32, 256, 0, stream>>>(x, W0, bufA, nullptr, nullptr);
    k_agg  <<<NN, 128, 0, stream>>>(bufA, row_ptr, csr_src, csr_w, dinv, b0, bufB);
    k_stats<<<NSB, 256, 0, stream>>>(bufB, psum, psq);
    k_nparams<<<1, 128, 0, stream>>>(psum, psq, gn0w, gn0b, gn0a, mulv, addv);

    // stage 2: h = relu(norm(B))@W1 ; agg+bias ; stats
    k_gemm <<<NN / 32, 256, 0, stream>>>(bufB, W1, bufA, mulv, addv);
    k_agg  <<<NN, 128, 0, stream>>>(bufA, row_ptr, csr_src, csr_w, dinv, b1, bufB);
    k_stats<<<NSB, 256, 0, stream>>>(bufB, psum, psq);
    k_nparams<<<1, 128, 0, stream>>>(psum, psq, gn1w, gn1b, gn1a, mulv, addv);

    // fused MLP head (norm+relu folded into load)
    k_mlp<<<NN / 32, 256, 0, stream>>>(bufB, lin0w, lin0b, lin1w, lin1b, mulv, addv, out);

    (void)in_sizes; (void)n_in; (void)out_size; (void)ws_size;
}

// Round 2
// 608.678 us; speedup vs baseline: 1.5453x; 1.5453x over previous
//
#include <hip/hip_runtime.h>

// ---------------- problem constants ----------------
#define NN 100000      // nodes
#define NE 1600000     // edges (without self loops)
#define DD 128         // feature dim
#define EPSV 1e-5f

#define NBLK_SCAN 391          // ceil(NN/256)
#define RPB 512                // rows per stats block
#define NSB 196                // ceil(NN/RPB)
#define NSTRIP 6250            // NN/16 row-strips for MFMA gemms

typedef __attribute__((ext_vector_type(8))) __bf16 bf16x8;
typedef __attribute__((ext_vector_type(4))) float f32x4;

union BF8 {                // bit-level construction of MFMA bf16 fragments
    ushort  us[8];
    uint    ui[4];
    uint4   u4;
    bf16x8  v;
};

__device__ __forceinline__ ushort f2bf(float f) {   // RNE fp32 -> bf16 bits
    uint u = __float_as_uint(f);
    return (ushort)((u + 0x7fffu + ((u >> 16) & 1u)) >> 16);
}
__device__ __forceinline__ float bflo(uint u) { return __uint_as_float(u << 16); }
__device__ __forceinline__ float bfhi(uint u) { return __uint_as_float(u & 0xffff0000u); }

// ---------------- graph build ----------------
__global__ void k_count(const int* __restrict__ col, int* __restrict__ counts) {
    int e = blockIdx.x * blockDim.x + threadIdx.x;
    if (e < NE) atomicAdd(&counts[col[e]], 1);
}

__global__ void k_dinv(const int* __restrict__ counts, float* __restrict__ dinv) {
    int i = blockIdx.x * blockDim.x + threadIdx.x;
    if (i < NN) dinv[i] = rsqrtf((float)(counts[i] + 1));   // +1 self loop
}

__global__ void k_scanA(const int* __restrict__ counts, int* __restrict__ excl,
                        int* __restrict__ blksum) {
    __shared__ int s[256];
    int tid = threadIdx.x;
    int i = blockIdx.x * 256 + tid;
    int v = (i < NN) ? counts[i] : 0;
    s[tid] = v;
    __syncthreads();
    for (int off = 1; off < 256; off <<= 1) {
        int t = (tid >= off) ? s[tid - off] : 0;
        __syncthreads();
        s[tid] += t;
        __syncthreads();
    }
    if (i < NN) excl[i] = s[tid] - v;
    if (tid == 255) blksum[blockIdx.x] = s[255];
}

__global__ void k_scanB(int* __restrict__ blksum) {
    __shared__ int s[512];
    int tid = threadIdx.x;
    int v = (tid < NBLK_SCAN) ? blksum[tid] : 0;
    s[tid] = v;
    __syncthreads();
    for (int off = 1; off < 512; off <<= 1) {
        int t = (tid >= off) ? s[tid - off] : 0;
        __syncthreads();
        s[tid] += t;
        __syncthreads();
    }
    if (tid < NBLK_SCAN) blksum[tid] = s[tid] - v;
}

__global__ void k_scanC(int* __restrict__ row_ptr, const int* __restrict__ blksum) {
    int i = blockIdx.x * 256 + threadIdx.x;
    if (i < NN) row_ptr[i] += blksum[blockIdx.x];
    if (i == 0) row_ptr[NN] = NE;
}

__global__ void k_scatter(const int* __restrict__ row, const int* __restrict__ col,
                          const int* __restrict__ row_ptr, int* __restrict__ cursor,
                          const float* __restrict__ dinv,
                          int* __restrict__ csr_src, float* __restrict__ csr_w) {
    int e = blockIdx.x * blockDim.x + threadIdx.x;
    if (e >= NE) return;
    int c = col[e], r = row[e];
    int pos = row_ptr[c] + atomicAdd(&cursor[c], 1);
    csr_src[pos] = r;
    csr_w[pos] = dinv[r] * dinv[c];
}

// ---------------- weight prep: W[128x128] fp32 -> B-fragment order bf16 ----------------
// Wf[(nt*4+kt)*64 + lane][j] = bf16( W[(kt*32 + quad*8 + j)*128 + nt*16 + (lane&15)] )
__global__ void k_prepw(const float* __restrict__ W, ushort* __restrict__ Wf) {
    int t = blockIdx.x * 256 + threadIdx.x;    // 0..2047
    int lane = t & 63;
    int kt = (t >> 6) & 3;
    int nt = t >> 8;
    int quad = lane >> 4;
    int n = nt * 16 + (lane & 15);
    BF8 f;
    #pragma unroll
    for (int j = 0; j < 8; j++)
        f.us[j] = f2bf(W[(kt * 32 + quad * 8 + j) * DD + n]);
    ((uint4*)Wf)[t] = f.u4;
}

// ---------------- GEMM1: Y_bf16[N,128] = bf16(X_f32) @ Wf ----------------
// 1 wave = 16 rows x 128 cols, K=128. No LDS. 4 waves/block.
__global__ __launch_bounds__(256)
void k_gemmA(const float* __restrict__ X, const ushort* __restrict__ Wf,
             ushort* __restrict__ Y) {
    int strip = blockIdx.x * 4 + (threadIdx.x >> 6);
    if (strip >= NSTRIP) return;
    int lane = threadIdx.x & 63;
    int quad = lane >> 4;
    int m = lane & 15;
    int row = strip * 16 + m;

    BF8 a[4];
    #pragma unroll
    for (int kt = 0; kt < 4; kt++) {
        const float* xp = X + (size_t)row * DD + kt * 32 + quad * 8;
        float4 v0 = *(const float4*)xp;
        float4 v1 = *(const float4*)(xp + 4);
        a[kt].us[0] = f2bf(v0.x); a[kt].us[1] = f2bf(v0.y);
        a[kt].us[2] = f2bf(v0.z); a[kt].us[3] = f2bf(v0.w);
        a[kt].us[4] = f2bf(v1.x); a[kt].us[5] = f2bf(v1.y);
        a[kt].us[6] = f2bf(v1.z); a[kt].us[7] = f2bf(v1.w);
    }

    #pragma unroll
    for (int nt = 0; nt < 8; nt++) {
        f32x4 acc = {0.f, 0.f, 0.f, 0.f};
        #pragma unroll
        for (int kt = 0; kt < 4; kt++) {
            BF8 b;
            b.u4 = ((const uint4*)Wf)[(nt * 4 + kt) * 64 + lane];
            acc = __builtin_amdgcn_mfma_f32_16x16x32_bf16(a[kt].v, b.v, acc, 0, 0, 0);
        }
        int colg = nt * 16 + m;
        #pragma unroll
        for (int r = 0; r < 4; r++)
            Y[(size_t)(strip * 16 + quad * 4 + r) * DD + colg] = f2bf(acc[r]);
    }
}

// ---------------- GEMM2: Y = bf16(relu(norm(X_bf16))) @ Wf ----------------
__global__ __launch_bounds__(256)
void k_gemmB(const uint* __restrict__ Xp, const ushort* __restrict__ Wf,
             const float* __restrict__ mul, const float* __restrict__ add,
             ushort* __restrict__ Y) {
    int strip = blockIdx.x * 4 + (threadIdx.x >> 6);
    if (strip >= NSTRIP) return;
    int lane = threadIdx.x & 63;
    int quad = lane >> 4;
    int m = lane & 15;
    int row = strip * 16 + m;

    BF8 a[4];
    #pragma unroll
    for (int kt = 0; kt < 4; kt++) {
        int f = kt * 32 + quad * 8;
        uint4 xu = *(const uint4*)(Xp + (size_t)row * 64 + kt * 16 + quad * 4);
        float4 m0 = *(const float4*)(mul + f);
        float4 m1 = *(const float4*)(mul + f + 4);
        float4 a0 = *(const float4*)(add + f);
        float4 a1 = *(const float4*)(add + f + 4);
        uint xs[4] = {xu.x, xu.y, xu.z, xu.w};
        float mm[8] = {m0.x, m0.y, m0.z, m0.w, m1.x, m1.y, m1.z, m1.w};
        float aa[8] = {a0.x, a0.y, a0.z, a0.w, a1.x, a1.y, a1.z, a1.w};
        #pragma unroll
        for (int p = 0; p < 4; p++) {
            float lo = bflo(xs[p]), hi = bfhi(xs[p]);
            a[kt].us[2 * p]     = f2bf(fmaxf(0.f, fmaf(lo, mm[2 * p],     aa[2 * p])));
            a[kt].us[2 * p + 1] = f2bf(fmaxf(0.f, fmaf(hi, mm[2 * p + 1], aa[2 * p + 1])));
        }
    }

    #pragma unroll
    for (int nt = 0; nt < 8; nt++) {
        f32x4 acc = {0.f, 0.f, 0.f, 0.f};
        #pragma unroll
        for (int kt = 0; kt < 4; kt++) {
            BF8 b;
            b.u4 = ((const uint4*)Wf)[(nt * 4 + kt) * 64 + lane];
            acc = __builtin_amdgcn_mfma_f32_16x16x32_bf16(a[kt].v, b.v, acc, 0, 0, 0);
        }
        int colg = nt * 16 + m;
        #pragma unroll
        for (int r = 0; r < 4; r++)
            Y[(size_t)(strip * 16 + quad * 4 + r) * DD + colg] = f2bf(acc[r]);
    }
}

// ---------------- aggregation (bf16 rows, 2 features/lane) ----------------
// Y[i] = sum_{e: col=i} h[src_e]*w_e + h[i]*dinv_i^2 + bias; output packed bf16x2
__global__ __launch_bounds__(128)
void k_agg2(const uint* __restrict__ H2,
            const int* __restrict__ row_ptr, const int* __restrict__ csr_src,
            const float* __restrict__ csr_w, const float* __restrict__ dinv,
            const float* __restrict__ bias, uint* __restrict__ Y2) {
    const int i = blockIdx.x * 2 + (threadIdx.x >> 6);   // NN even
    const int lane = threadIdx.x & 63;
    const int p0 = row_ptr[i], p1 = row_ptr[i + 1];
    const float di = dinv[i];
    const float di2 = di * di;
    uint su = H2[(size_t)i * 64 + lane];
    float acc0 = bflo(su) * di2;
    float acc1 = bfhi(su) * di2;
    for (int p = p0; p < p1; p += 64) {
        int navail = p1 - p;
        int srcv = 0; float wv = 0.f;
        if (lane < navail) { srcv = csr_src[p + lane]; wv = csr_w[p + lane]; }
        int mcnt = navail < 64 ? navail : 64;
        for (int j = 0; j < mcnt; j++) {
            int s = __shfl(srcv, j, 64);
            float w = __shfl(wv, j, 64);
            uint hu = H2[(size_t)s * 64 + lane];
            acc0 = fmaf(bflo(hu), w, acc0);
            acc1 = fmaf(bfhi(hu), w, acc1);
        }
    }
    float2 bb = *(const float2*)(bias + 2 * lane);
    acc0 += bb.x; acc1 += bb.y;
    Y2[(size_t)i * 64 + lane] = (uint)f2bf(acc0) | ((uint)f2bf(acc1) << 16);
}

// ---------------- GraphNorm stats over bf16 buffer ----------------
__global__ __launch_bounds__(256)
void k_stats(const uint* __restrict__ Xp, float* __restrict__ psum, float* __restrict__ psq) {
    __shared__ float shs[4][128], shq[4][128];
    int lane = threadIdx.x & 63;
    int grp = threadIdx.x >> 6;
    int r0 = blockIdx.x * RPB;
    int rend = r0 + RPB; if (rend > NN) rend = NN;
    float s0 = 0.f, s1 = 0.f, q0 = 0.f, q1 = 0.f;
    for (int r = r0 + grp; r < rend; r += 4) {
        uint u = Xp[(size_t)r * 64 + lane];
        float a = bflo(u), b = bfhi(u);
        s0 += a; q0 = fmaf(a, a, q0);
        s1 += b; q1 = fmaf(b, b, q1);
    }
    shs[grp][2 * lane] = s0; shs[grp][2 * lane + 1] = s1;
    shq[grp][2 * lane] = q0; shq[grp][2 * lane + 1] = q1;
    __syncthreads();
    if (threadIdx.x < 128) {
        int f = threadIdx.x;
        psum[blockIdx.x * DD + f] = shs[0][f] + shs[1][f] + shs[2][f] + shs[3][f];
        psq[blockIdx.x * DD + f]  = shq[0][f] + shq[1][f] + shq[2][f] + shq[3][f];
    }
}

__global__ void k_nparams(const float* __restrict__ psum, const float* __restrict__ psq,
                          const float* __restrict__ w, const float* __restrict__ b,
                          const float* __restrict__ a,
                          float* __restrict__ mul, float* __restrict__ add) {
    int f = threadIdx.x;
    float s = 0.f, q = 0.f;
    for (int j = 0; j < NSB; j++) { s += psum[j * DD + f]; q += psq[j * DD + f]; }
    const float invn = 1.0f / (float)NN;
    float m = s * invn;
    float ex2 = q * invn;
    float av = a[f];
    float var = ex2 - m * m * (2.f * av - av * av);
    float inv = rsqrtf(var + EPSV);
    mul[f] = w[f] * inv;
    add[f] = b[f] - w[f] * inv * av * m;
}

// ---------------- fused MLP head (MFMA): out = relu(T(X)@W + b0h) @ v1 + b1 ----------------
__global__ __launch_bounds__(256)
void k_mlp(const uint* __restrict__ Xp, const ushort* __restrict__ Wf,
           const float* __restrict__ mul, const float* __restrict__ add,
           const float* __restrict__ b0h, const float* __restrict__ v1,
           const float* __restrict__ b1, float* __restrict__ out) {
    int strip = blockIdx.x * 4 + (threadIdx.x >> 6);
    if (strip >= NSTRIP) return;
    int lane = threadIdx.x & 63;
    int quad = lane >> 4;
    int m = lane & 15;
    int row = strip * 16 + m;

    BF8 a[4];
    #pragma unroll
    for (int kt = 0; kt < 4; kt++) {
        int f = kt * 32 + quad * 8;
        uint4 xu = *(const uint4*)(Xp + (size_t)row * 64 + kt * 16 + quad * 4);
        float4 m0 = *(const float4*)(mul + f);
        float4 m1 = *(const float4*)(mul + f + 4);
        float4 a0 = *(const float4*)(add + f);
        float4 a1 = *(const float4*)(add + f + 4);
        uint xs[4] = {xu.x, xu.y, xu.z, xu.w};
        float mm[8] = {m0.x, m0.y, m0.z, m0.w, m1.x, m1.y, m1.z, m1.w};
        float aa[8] = {a0.x, a0.y, a0.z, a0.w, a1.x, a1.y, a1.z, a1.w};
        #pragma unroll
        for (int p = 0; p < 4; p++) {
            float lo = bflo(xs[p]), hi = bfhi(xs[p]);
            a[kt].us[2 * p]     = f2bf(fmaxf(0.f, fmaf(lo, mm[2 * p],     aa[2 * p])));
            a[kt].us[2 * p + 1] = f2bf(fmaxf(0.f, fmaf(hi, mm[2 * p + 1], aa[2 * p + 1])));
        }
    }

    float part[4] = {0.f, 0.f, 0.f, 0.f};
    #pragma unroll
    for (int nt = 0; nt < 8; nt++) {
        f32x4 acc = {0.f, 0.f, 0.f, 0.f};
        #pragma unroll
        for (int kt = 0; kt < 4; kt++) {
            BF8 b;
            b.u4 = ((const uint4*)Wf)[(nt * 4 + kt) * 64 + lane];
            acc = __builtin_amdgcn_mfma_f32_16x16x32_bf16(a[kt].v, b.v, acc, 0, 0, 0);
        }
        int colg = nt * 16 + m;
        float bb = b0h[colg];
        float vv = v1[colg];
        #pragma unroll
        for (int r = 0; r < 4; r++)
            part[r] = fmaf(fmaxf(0.f, acc[r] + bb), vv, part[r]);
    }
    #pragma unroll
    for (int r = 0; r < 4; r++) {
        #pragma unroll
        for (int off = 1; off < 16; off <<= 1)
            part[r] += __shfl_xor(part[r], off, 64);
    }
    if (m == 0) {
        float ob = b1[0];
        #pragma unroll
        for (int r = 0; r < 4; r++)
            out[strip * 16 + quad * 4 + r] = part[r] + ob;
    }
}

// ---------------- launch ----------------
static inline char* wsalloc(char*& p, size_t bytes) {
    char* r = p;
    p += (bytes + 255) & ~(size_t)255;
    return r;
}

extern "C" void kernel_launch(void* const* d_in, const int* in_sizes, int n_in,
                              void* d_out, int out_size, void* d_ws, size_t ws_size,
                              hipStream_t stream) {
    const float* x     = (const float*)d_in[0];
    const int*   ei    = (const int*)d_in[1];
    const int*   row   = ei;
    const int*   col   = ei + NE;
    const float* W0    = (const float*)d_in[2];
    const float* b0    = (const float*)d_in[3];
    const float* W1    = (const float*)d_in[4];
    const float* b1    = (const float*)d_in[5];
    const float* gn0w  = (const float*)d_in[6];
    const float* gn0b  = (const float*)d_in[7];
    const float* gn0a  = (const float*)d_in[8];
    const float* gn1w  = (const float*)d_in[9];
    const float* gn1b  = (const float*)d_in[10];
    const float* gn1a  = (const float*)d_in[11];
    const float* lin0w = (const float*)d_in[12];
    const float* lin0b = (const float*)d_in[13];
    const float* lin1w = (const float*)d_in[14];
    const float* lin1b = (const float*)d_in[15];
    float* out = (float*)d_out;

    char* p = (char*)d_ws;
    ushort* bufA   = (ushort*)wsalloc(p, (size_t)NN * DD * 2);   // bf16 h
    ushort* bufB   = (ushort*)wsalloc(p, (size_t)NN * DD * 2);   // bf16 agg out
    int*    csr_src= (int*)   wsalloc(p, (size_t)NE * 4);
    float*  csr_w  = (float*) wsalloc(p, (size_t)NE * 4);
    int*    counts = (int*)   wsalloc(p, (size_t)NN * 4);
    int*    row_ptr= (int*)   wsalloc(p, (size_t)(NN + 1) * 4);
    int*    cursor = (int*)   wsalloc(p, (size_t)NN * 4);
    float*  dinv   = (float*) wsalloc(p, (size_t)NN * 4);
    int*    blksum = (int*)   wsalloc(p, 512 * 4);
    float*  psum   = (float*) wsalloc(p, (size_t)NSB * DD * 4);
    float*  psq    = (float*) wsalloc(p, (size_t)NSB * DD * 4);
    float*  mulv   = (float*) wsalloc(p, DD * 4);
    float*  addv   = (float*) wsalloc(p, DD * 4);
    ushort* Wf0    = (ushort*)wsalloc(p, 8 * 4 * 64 * 8 * 2);
    ushort* Wf1    = (ushort*)wsalloc(p, 8 * 4 * 64 * 8 * 2);
    ushort* Wf2    = (ushort*)wsalloc(p, 8 * 4 * 64 * 8 * 2);

    hipMemsetAsync(counts, 0, (size_t)NN * 4, stream);
    hipMemsetAsync(cursor, 0, (size_t)NN * 4, stream);

    // graph build
    k_count  <<<(NE + 255) / 256, 256, 0, stream>>>(col, counts);
    k_dinv   <<<(NN + 255) / 256, 256, 0, stream>>>(counts, dinv);
    k_scanA  <<<NBLK_SCAN, 256, 0, stream>>>(counts, row_ptr, blksum);
    k_scanB  <<<1, 512, 0, stream>>>(blksum);
    k_scanC  <<<NBLK_SCAN, 256, 0, stream>>>(row_ptr, blksum);
    k_scatter<<<(NE + 255) / 256, 256, 0, stream>>>(row, col, row_ptr, cursor, dinv,
                                                    csr_src, csr_w);

    // weight prep (independent of graph build)
    k_prepw<<<8, 256, 0, stream>>>(W0, Wf0);
    k_prepw<<<8, 256, 0, stream>>>(W1, Wf1);
    k_prepw<<<8, 256, 0, stream>>>(lin0w, Wf2);

    const int GB = (NSTRIP + 3) / 4;   // 1563 blocks for gemm-shaped kernels

    // stage 1
    k_gemmA<<<GB, 256, 0, stream>>>(x, Wf0, bufA);
    k_agg2 <<<NN / 2, 128, 0, stream>>>((const uint*)bufA, row_ptr, csr_src, csr_w,
                                        dinv, b0, (uint*)bufB);
    k_stats<<<NSB, 256, 0, stream>>>((const uint*)bufB, psum, psq);
    k_nparams<<<1, 128, 0, stream>>>(psum, psq, gn0w, gn0b, gn0a, mulv, addv);

    // stage 2
    k_gemmB<<<GB, 256, 0, stream>>>((const uint*)bufB, Wf1, mulv, addv, bufA);
    k_agg2 <<<NN / 2, 128, 0, stream>>>((const uint*)bufA, row_ptr, csr_src, csr_w,
                                        dinv, b1, (uint*)bufB);
    k_stats<<<NSB, 256, 0, stream>>>((const uint*)bufB, psum, psq);
    k_nparams<<<1, 128, 0, stream>>>(psum, psq, gn1w, gn1b, gn1a, mulv, addv);

    // fused MLP head
    k_mlp<<<GB, 256, 0, stream>>>((const uint*)bufB, Wf2, mulv, addv,
                                  lin0b, lin1w, lin1b, out);

    (void)in_sizes; (void)n_in; (void)out_size; (void)ws_size;
}

// Round 3
// 549.141 us; speedup vs baseline: 1.7129x; 1.1084x over previous
//
#include <hip/hip_runtime.h>

// ---------------- problem constants ----------------
#define NN 100000      // nodes
#define NE 1600000     // edges (without self loops)
#define DD 128         // feature dim
#define EPSV 1e-5f

#define NBLK_SCAN 391          // ceil(NN/256)
#define RPB 512                // rows per stats block
#define NSB 196                // ceil(NN/RPB)
#define NSTRIP 6250            // NN/16 row-strips for MFMA gemms

typedef __attribute__((ext_vector_type(8))) __bf16 bf16x8;
typedef __attribute__((ext_vector_type(4))) float f32x4;

union BF8 {                // bit-level construction of MFMA bf16 fragments
    ushort  us[8];
    uint    ui[4];
    uint4   u4;
    bf16x8  v;
};

__device__ __forceinline__ ushort f2bf(float f) {   // RNE fp32 -> bf16 bits
    uint u = __float_as_uint(f);
    return (ushort)((u + 0x7fffu + ((u >> 16) & 1u)) >> 16);
}
__device__ __forceinline__ float bflo(uint u) { return __uint_as_float(u << 16); }
__device__ __forceinline__ float bfhi(uint u) { return __uint_as_float(u & 0xffff0000u); }

// ---------------- graph build ----------------
__global__ void k_count(const int* __restrict__ col, int* __restrict__ counts) {
    int e = blockIdx.x * blockDim.x + threadIdx.x;
    if (e < NE) atomicAdd(&counts[col[e]], 1);
}

// block-local exclusive scan of counts; also emits dinv (fused old k_dinv)
__global__ void k_scanA(const int* __restrict__ counts, int* __restrict__ excl,
                        int* __restrict__ blksum, float* __restrict__ dinv) {
    __shared__ int s[256];
    int tid = threadIdx.x;
    int i = blockIdx.x * 256 + tid;
    int v = (i < NN) ? counts[i] : 0;
    s[tid] = v;
    __syncthreads();
    for (int off = 1; off < 256; off <<= 1) {
        int t = (tid >= off) ? s[tid - off] : 0;
        __syncthreads();
        s[tid] += t;
        __syncthreads();
    }
    if (i < NN) {
        excl[i] = s[tid] - v;
        dinv[i] = rsqrtf((float)(v + 1));   // +1 self loop
    }
    if (tid == 255) blksum[blockIdx.x] = s[255];
}

__global__ void k_scanB(int* __restrict__ blksum) {
    __shared__ int s[512];
    int tid = threadIdx.x;
    int v = (tid < NBLK_SCAN) ? blksum[tid] : 0;
    s[tid] = v;
    __syncthreads();
    for (int off = 1; off < 512; off <<= 1) {
        int t = (tid >= off) ? s[tid - off] : 0;
        __syncthreads();
        s[tid] += t;
        __syncthreads();
    }
    if (tid < NBLK_SCAN) blksum[tid] = s[tid] - v;
}

__global__ void k_scanC(int* __restrict__ row_ptr, const int* __restrict__ blksum) {
    int i = blockIdx.x * 256 + threadIdx.x;
    if (i < NN) row_ptr[i] += blksum[blockIdx.x];
    if (i == 0) row_ptr[NN] = NE;
}

// CSR record: {src, dinv[src] bits} in ONE 8B store (halves random-write line touches)
__global__ void k_scatter(const int* __restrict__ row, const int* __restrict__ col,
                          const int* __restrict__ row_ptr, int* __restrict__ cursor,
                          const float* __restrict__ dinv, int2* __restrict__ csr) {
    int e = blockIdx.x * blockDim.x + threadIdx.x;
    if (e >= NE) return;
    int c = col[e], r = row[e];
    int pos = row_ptr[c] + atomicAdd(&cursor[c], 1);
    csr[pos] = make_int2(r, __float_as_int(dinv[r]));
}

// ---------------- weight prep: 3x W[128x128] fp32 -> B-fragment order bf16 ----------------
// Wf[(nt*4+kt)*64 + lane][j] = bf16( W[(kt*32 + quad*8 + j)*128 + nt*16 + (lane&15)] )
__global__ void k_prepw3(const float* __restrict__ WA, const float* __restrict__ WB,
                         const float* __restrict__ WC, ushort* __restrict__ Wf) {
    int which = blockIdx.x >> 3;
    const float* W = (which == 0) ? WA : ((which == 1) ? WB : WC);
    int t = (blockIdx.x & 7) * 256 + threadIdx.x;    // 0..2047
    int lane = t & 63;
    int kt = (t >> 6) & 3;
    int nt = t >> 8;
    int quad = lane >> 4;
    int n = nt * 16 + (lane & 15);
    BF8 f;
    #pragma unroll
    for (int j = 0; j < 8; j++)
        f.us[j] = f2bf(W[(kt * 32 + quad * 8 + j) * DD + n]);
    ((uint4*)(Wf + (size_t)which * 2048 * 8))[t] = f.u4;
}

// ---------------- GEMM1: Y_bf16[N,128] = bf16(X_f32) @ Wf ----------------
__global__ __launch_bounds__(256)
void k_gemmA(const float* __restrict__ X, const ushort* __restrict__ Wf,
             ushort* __restrict__ Y) {
    int strip = blockIdx.x * 4 + (threadIdx.x >> 6);
    if (strip >= NSTRIP) return;
    int lane = threadIdx.x & 63;
    int quad = lane >> 4;
    int m = lane & 15;
    int row = strip * 16 + m;

    BF8 a[4];
    #pragma unroll
    for (int kt = 0; kt < 4; kt++) {
        const float* xp = X + (size_t)row * DD + kt * 32 + quad * 8;
        float4 v0 = *(const float4*)xp;
        float4 v1 = *(const float4*)(xp + 4);
        a[kt].us[0] = f2bf(v0.x); a[kt].us[1] = f2bf(v0.y);
        a[kt].us[2] = f2bf(v0.z); a[kt].us[3] = f2bf(v0.w);
        a[kt].us[4] = f2bf(v1.x); a[kt].us[5] = f2bf(v1.y);
        a[kt].us[6] = f2bf(v1.z); a[kt].us[7] = f2bf(v1.w);
    }

    #pragma unroll
    for (int nt = 0; nt < 8; nt++) {
        f32x4 acc = {0.f, 0.f, 0.f, 0.f};
        #pragma unroll
        for (int kt = 0; kt < 4; kt++) {
            BF8 b;
            b.u4 = ((const uint4*)Wf)[(nt * 4 + kt) * 64 + lane];
            acc = __builtin_amdgcn_mfma_f32_16x16x32_bf16(a[kt].v, b.v, acc, 0, 0, 0);
        }
        int colg = nt * 16 + m;
        #pragma unroll
        for (int r = 0; r < 4; r++)
            Y[(size_t)(strip * 16 + quad * 4 + r) * DD + colg] = f2bf(acc[r]);
    }
}

// ---------------- GEMM2: Y = bf16(relu(norm(X_bf16))) @ Wf ----------------
__global__ __launch_bounds__(256)
void k_gemmB(const uint* __restrict__ Xp, const ushort* __restrict__ Wf,
             const float* __restrict__ mul, const float* __restrict__ add,
             ushort* __restrict__ Y) {
    int strip = blockIdx.x * 4 + (threadIdx.x >> 6);
    if (strip >= NSTRIP) return;
    int lane = threadIdx.x & 63;
    int quad = lane >> 4;
    int m = lane & 15;
    int row = strip * 16 + m;

    BF8 a[4];
    #pragma unroll
    for (int kt = 0; kt < 4; kt++) {
        int f = kt * 32 + quad * 8;
        uint4 xu = *(const uint4*)(Xp + (size_t)row * 64 + kt * 16 + quad * 4);
        float4 m0 = *(const float4*)(mul + f);
        float4 m1 = *(const float4*)(mul + f + 4);
        float4 a0 = *(const float4*)(add + f);
        float4 a1 = *(const float4*)(add + f + 4);
        uint xs[4] = {xu.x, xu.y, xu.z, xu.w};
        float mm[8] = {m0.x, m0.y, m0.z, m0.w, m1.x, m1.y, m1.z, m1.w};
        float aa[8] = {a0.x, a0.y, a0.z, a0.w, a1.x, a1.y, a1.z, a1.w};
        #pragma unroll
        for (int p = 0; p < 4; p++) {
            float lo = bflo(xs[p]), hi = bfhi(xs[p]);
            a[kt].us[2 * p]     = f2bf(fmaxf(0.f, fmaf(lo, mm[2 * p],     aa[2 * p])));
            a[kt].us[2 * p + 1] = f2bf(fmaxf(0.f, fmaf(hi, mm[2 * p + 1], aa[2 * p + 1])));
        }
    }

    #pragma unroll
    for (int nt = 0; nt < 8; nt++) {
        f32x4 acc = {0.f, 0.f, 0.f, 0.f};
        #pragma unroll
        for (int kt = 0; kt < 4; kt++) {
            BF8 b;
            b.u4 = ((const uint4*)Wf)[(nt * 4 + kt) * 64 + lane];
            acc = __builtin_amdgcn_mfma_f32_16x16x32_bf16(a[kt].v, b.v, acc, 0, 0, 0);
        }
        int colg = nt * 16 + m;
        #pragma unroll
        for (int r = 0; r < 4; r++)
            Y[(size_t)(strip * 16 + quad * 4 + r) * DD + colg] = f2bf(acc[r]);
    }
}

// ---------------- aggregation (bf16 rows, scalarized edge stream) ----------------
// Y[i] = di*( sum_e h[src_e]*dinv[src_e] + h[i]*di ) + bias
__global__ __launch_bounds__(128)
void k_agg2(const uint* __restrict__ H2,
            const int* __restrict__ row_ptr, const int2* __restrict__ csr,
            const float* __restrict__ dinv,
            const float* __restrict__ bias, uint* __restrict__ Y2) {
    const int lane = threadIdx.x & 63;
    // node index is wave-uniform: force into SGPR so row_ptr/csr loads scalarize
    const int i = __builtin_amdgcn_readfirstlane(blockIdx.x * 2 + (threadIdx.x >> 6));
    const int p0 = row_ptr[i], p1 = row_ptr[i + 1];
    const float di = dinv[i];
    uint su = H2[(size_t)i * 64 + lane];
    float a0 = bflo(su) * di, a1 = bfhi(su) * di;   // self loop (x di again at end)
    float b0 = 0.f, b1 = 0.f;
    int p = p0;
    for (; p + 1 < p1; p += 2) {                    // two independent chains
        int2 e0 = csr[p];
        int2 e1 = csr[p + 1];
        uint h0 = H2[(size_t)e0.x * 64 + lane];
        uint h1 = H2[(size_t)e1.x * 64 + lane];
        float w0 = __int_as_float(e0.y);
        float w1 = __int_as_float(e1.y);
        a0 = fmaf(bflo(h0), w0, a0); a1 = fmaf(bfhi(h0), w0, a1);
        b0 = fmaf(bflo(h1), w1, b0); b1 = fmaf(bfhi(h1), w1, b1);
    }
    if (p < p1) {
        int2 e0 = csr[p];
        uint h0 = H2[(size_t)e0.x * 64 + lane];
        float w0 = __int_as_float(e0.y);
        a0 = fmaf(bflo(h0), w0, a0); a1 = fmaf(bfhi(h0), w0, a1);
    }
    float2 bb = *(const float2*)(bias + 2 * lane);
    float r0 = fmaf(a0 + b0, di, bb.x);
    float r1 = fmaf(a1 + b1, di, bb.y);
    Y2[(size_t)i * 64 + lane] = (uint)f2bf(r0) | ((uint)f2bf(r1) << 16);
}

// ---------------- GraphNorm stats over bf16 buffer ----------------
__global__ __launch_bounds__(256)
void k_stats(const uint* __restrict__ Xp, float* __restrict__ psum, float* __restrict__ psq) {
    __shared__ float shs[4][128], shq[4][128];
    int lane = threadIdx.x & 63;
    int grp = threadIdx.x >> 6;
    int r0 = blockIdx.x * RPB;
    int rend = r0 + RPB; if (rend > NN) rend = NN;
    float s0 = 0.f, s1 = 0.f, q0 = 0.f, q1 = 0.f;
    for (int r = r0 + grp; r < rend; r += 4) {
        uint u = Xp[(size_t)r * 64 + lane];
        float a = bflo(u), b = bfhi(u);
        s0 += a; q0 = fmaf(a, a, q0);
        s1 += b; q1 = fmaf(b, b, q1);
    }
    shs[grp][2 * lane] = s0; shs[grp][2 * lane + 1] = s1;
    shq[grp][2 * lane] = q0; shq[grp][2 * lane + 1] = q1;
    __syncthreads();
    if (threadIdx.x < 128) {
        int f = threadIdx.x;
        psum[blockIdx.x * DD + f] = shs[0][f] + shs[1][f] + shs[2][f] + shs[3][f];
        psq[blockIdx.x * DD + f]  = shq[0][f] + shq[1][f] + shq[2][f] + shq[3][f];
    }
}

__global__ void k_nparams(const float* __restrict__ psum, const float* __restrict__ psq,
                          const float* __restrict__ w, const float* __restrict__ b,
                          const float* __restrict__ a,
                          float* __restrict__ mul, float* __restrict__ add) {
    int f = threadIdx.x;
    float s = 0.f, q = 0.f;
    for (int j = 0; j < NSB; j++) { s += psum[j * DD + f]; q += psq[j * DD + f]; }
    const float invn = 1.0f / (float)NN;
    float m = s * invn;
    float ex2 = q * invn;
    float av = a[f];
    float var = ex2 - m * m * (2.f * av - av * av);
    float inv = rsqrtf(var + EPSV);
    mul[f] = w[f] * inv;
    add[f] = b[f] - w[f] * inv * av * m;
}

// ---------------- fused MLP head (MFMA): out = relu(T(X)@W + b0h) @ v1 + b1 ----------------
__global__ __launch_bounds__(256)
void k_mlp(const uint* __restrict__ Xp, const ushort* __restrict__ Wf,
           const float* __restrict__ mul, const float* __restrict__ add,
           const float* __restrict__ b0h, const float* __restrict__ v1,
           const float* __restrict__ b1, float* __restrict__ out) {
    int strip = blockIdx.x * 4 + (threadIdx.x >> 6);
    if (strip >= NSTRIP) return;
    int lane = threadIdx.x & 63;
    int quad = lane >> 4;
    int m = lane & 15;
    int row = strip * 16 + m;

    BF8 a[4];
    #pragma unroll
    for (int kt = 0; kt < 4; kt++) {
        int f = kt * 32 + quad * 8;
        uint4 xu = *(const uint4*)(Xp + (size_t)row * 64 + kt * 16 + quad * 4);
        float4 m0 = *(const float4*)(mul + f);
        float4 m1 = *(const float4*)(mul + f + 4);
        float4 a0 = *(const float4*)(add + f);
        float4 a1 = *(const float4*)(add + f + 4);
        uint xs[4] = {xu.x, xu.y, xu.z, xu.w};
        float mm[8] = {m0.x, m0.y, m0.z, m0.w, m1.x, m1.y, m1.z, m1.w};
        float aa[8] = {a0.x, a0.y, a0.z, a0.w, a1.x, a1.y, a1.z, a1.w};
        #pragma unroll
        for (int p = 0; p < 4; p++) {
            float lo = bflo(xs[p]), hi = bfhi(xs[p]);
            a[kt].us[2 * p]     = f2bf(fmaxf(0.f, fmaf(lo, mm[2 * p],     aa[2 * p])));
            a[kt].us[2 * p + 1] = f2bf(fmaxf(0.f, fmaf(hi, mm[2 * p + 1], aa[2 * p + 1])));
        }
    }

    float part[4] = {0.f, 0.f, 0.f, 0.f};
    #pragma unroll
    for (int nt = 0; nt < 8; nt++) {
        f32x4 acc = {0.f, 0.f, 0.f, 0.f};
        #pragma unroll
        for (int kt = 0; kt < 4; kt++) {
            BF8 b;
            b.u4 = ((const uint4*)Wf)[(nt * 4 + kt) * 64 + lane];
            acc = __builtin_amdgcn_mfma_f32_16x16x32_bf16(a[kt].v, b.v, acc, 0, 0, 0);
        }
        int colg = nt * 16 + m;
        float bb = b0h[colg];
        float vv = v1[colg];
        #pragma unroll
        for (int r = 0; r < 4; r++)
            part[r] = fmaf(fmaxf(0.f, acc[r] + bb), vv, part[r]);
    }
    #pragma unroll
    for (int r = 0; r < 4; r++) {
        #pragma unroll
        for (int off = 1; off < 16; off <<= 1)
            part[r] += __shfl_xor(part[r], off, 64);
    }
    if (m == 0) {
        float ob = b1[0];
        #pragma unroll
        for (int r = 0; r < 4; r++)
            out[strip * 16 + quad * 4 + r] = part[r] + ob;
    }
}

// ---------------- launch ----------------
static inline char* wsalloc(char*& p, size_t bytes) {
    char* r = p;
    p += (bytes + 255) & ~(size_t)255;
    return r;
}

extern "C" void kernel_launch(void* const* d_in, const int* in_sizes, int n_in,
                              void* d_out, int out_size, void* d_ws, size_t ws_size,
                              hipStream_t stream) {
    const float* x     = (const float*)d_in[0];
    const int*   ei    = (const int*)d_in[1];
    const int*   row   = ei;
    const int*   col   = ei + NE;
    const float* W0    = (const float*)d_in[2];
    const float* b0    = (const float*)d_in[3];
    const float* W1    = (const float*)d_in[4];
    const float* b1    = (const float*)d_in[5];
    const float* gn0w  = (const float*)d_in[6];
    const float* gn0b  = (const float*)d_in[7];
    const float* gn0a  = (const float*)d_in[8];
    const float* gn1w  = (const float*)d_in[9];
    const float* gn1b  = (const float*)d_in[10];
    const float* gn1a  = (const float*)d_in[11];
    const float* lin0w = (const float*)d_in[12];
    const float* lin0b = (const float*)d_in[13];
    const float* lin1w = (const float*)d_in[14];
    const float* lin1b = (const float*)d_in[15];
    float* out = (float*)d_out;

    char* p = (char*)d_ws;
    ushort* bufA   = (ushort*)wsalloc(p, (size_t)NN * DD * 2);   // bf16 h
    ushort* bufB   = (ushort*)wsalloc(p, (size_t)NN * DD * 2);   // bf16 agg out
    int2*   csr    = (int2*)  wsalloc(p, (size_t)NE * 8);        // {src, dinv[src]}
    int*    counts = (int*)   wsalloc(p, (size_t)NN * 4);
    int*    cursor = (int*)   wsalloc(p, (size_t)NN * 4);        // adjacent: one memset
    int*    row_ptr= (int*)   wsalloc(p, (size_t)(NN + 1) * 4);
    float*  dinv   = (float*) wsalloc(p, (size_t)NN * 4);
    int*    blksum = (int*)   wsalloc(p, 512 * 4);
    float*  psum   = (float*) wsalloc(p, (size_t)NSB * DD * 4);
    float*  psq    = (float*) wsalloc(p, (size_t)NSB * DD * 4);
    float*  mulv   = (float*) wsalloc(p, DD * 4);
    float*  addv   = (float*) wsalloc(p, DD * 4);
    ushort* Wf     = (ushort*)wsalloc(p, 3 * 2048 * 8 * 2);      // 3 prepped weights

    // counts and cursor are adjacent 256B-aligned allocations: single memset
    hipMemsetAsync(counts, 0, 2 * (((size_t)NN * 4 + 255) & ~(size_t)255), stream);

    // graph build
    k_count  <<<(NE + 255) / 256, 256, 0, stream>>>(col, counts);
    k_scanA  <<<NBLK_SCAN, 256, 0, stream>>>(counts, row_ptr, blksum, dinv);
    k_scanB  <<<1, 512, 0, stream>>>(blksum);
    k_scanC  <<<NBLK_SCAN, 256, 0, stream>>>(row_ptr, blksum);
    k_scatter<<<(NE + 255) / 256, 256, 0, stream>>>(row, col, row_ptr, cursor, dinv, csr);

    // weight prep (independent of graph build)
    k_prepw3<<<24, 256, 0, stream>>>(W0, W1, lin0w, Wf);
    ushort* Wf0 = Wf;
    ushort* Wf1 = Wf + 2048 * 8;
    ushort* Wf2 = Wf + 2 * 2048 * 8;

    const int GB = (NSTRIP + 3) / 4;   // 1563 blocks for gemm-shaped kernels

    // stage 1
    k_gemmA<<<GB, 256, 0, stream>>>(x, Wf0, bufA);
    k_agg2 <<<NN / 2, 128, 0, stream>>>((const uint*)bufA, row_ptr, csr, dinv, b0,
                                        (uint*)bufB);
    k_stats<<<NSB, 256, 0, stream>>>((const uint*)bufB, psum, psq);
    k_nparams<<<1, 128, 0, stream>>>(psum, psq, gn0w, gn0b, gn0a, mulv, addv);

    // stage 2
    k_gemmB<<<GB, 256, 0, stream>>>((const uint*)bufB, Wf1, mulv, addv, bufA);
    k_agg2 <<<NN / 2, 128, 0, stream>>>((const uint*)bufA, row_ptr, csr, dinv, b1,
                                        (uint*)bufB);
    k_stats<<<NSB, 256, 0, stream>>>((const uint*)bufB, psum, psq);
    k_nparams<<<1, 128, 0, stream>>>(psum, psq, gn1w, gn1b, gn1a, mulv, addv);

    // fused MLP head
    k_mlp<<<GB, 256, 0, stream>>>((const uint*)bufB, Wf2, mulv, addv,
                                  lin0b, lin1w, lin1b, out);

    (void)in_sizes; (void)n_in; (void)out_size; (void)ws_size;
}

// Round 4
// 503.391 us; speedup vs baseline: 1.8685x; 1.0909x over previous
//
#include <hip/hip_runtime.h>

// ---------------- problem constants ----------------
#define NN 100000      // nodes
#define NE 1600000     // edges (without self loops)
#define DD 128         // feature dim
#define EPSV 1e-5f

#define NBLK_SCAN 391          // ceil(NN/256)
#define RPB 512                // rows per stats block
#define NSB 196                // ceil(NN/RPB)
#define NSTRIP 6250            // NN/16 row-strips for MFMA gemms

// bucket sort: 196 buckets of 512 nodes; 782 hist/place blocks of 2048 edges
#define BSHIFT 9
#define NBUCK 196
#define EPB 2048
#define NHB 782

typedef __attribute__((ext_vector_type(8))) __bf16 bf16x8;
typedef __attribute__((ext_vector_type(4))) float f32x4;

union BF8 {                // bit-level construction of MFMA bf16 fragments
    ushort  us[8];
    uint    ui[4];
    uint4   u4;
    bf16x8  v;
};

__device__ __forceinline__ ushort f2bf(float f) {   // RNE fp32 -> bf16 bits
    uint u = __float_as_uint(f);
    return (ushort)((u + 0x7fffu + ((u >> 16) & 1u)) >> 16);
}
__device__ __forceinline__ float bflo(uint u) { return __uint_as_float(u << 16); }
__device__ __forceinline__ float bfhi(uint u) { return __uint_as_float(u & 0xffff0000u); }

// ---------------- graph build: degree ----------------
__global__ void k_count(const int* __restrict__ col, int* __restrict__ counts) {
    int e = blockIdx.x * blockDim.x + threadIdx.x;
    if (e < NE) atomicAdd(&counts[col[e]], 1);
}

// block-local exclusive scan of counts; also emits dinv
__global__ void k_scanA(const int* __restrict__ counts, int* __restrict__ excl,
                        int* __restrict__ blksum, float* __restrict__ dinv) {
    __shared__ int s[256];
    int tid = threadIdx.x;
    int i = blockIdx.x * 256 + tid;
    int v = (i < NN) ? counts[i] : 0;
    s[tid] = v;
    __syncthreads();
    for (int off = 1; off < 256; off <<= 1) {
        int t = (tid >= off) ? s[tid - off] : 0;
        __syncthreads();
        s[tid] += t;
        __syncthreads();
    }
    if (i < NN) {
        excl[i] = s[tid] - v;
        dinv[i] = rsqrtf((float)(v + 1));   // +1 self loop
    }
    if (tid == 255) blksum[blockIdx.x] = s[255];
}

__global__ void k_scanB(int* __restrict__ blksum) {
    __shared__ int s[512];
    int tid = threadIdx.x;
    int v = (tid < NBLK_SCAN) ? blksum[tid] : 0;
    s[tid] = v;
    __syncthreads();
    for (int off = 1; off < 512; off <<= 1) {
        int t = (tid >= off) ? s[tid - off] : 0;
        __syncthreads();
        s[tid] += t;
        __syncthreads();
    }
    if (tid < NBLK_SCAN) blksum[tid] = s[tid] - v;
}

__global__ void k_scanC(int* __restrict__ row_ptr, const int* __restrict__ blksum) {
    int i = blockIdx.x * 256 + threadIdx.x;
    if (i < NN) row_ptr[i] += blksum[blockIdx.x];
    if (i == 0) row_ptr[NN] = NE;
}

// ---------------- bucketed counting sort (write-locality CSR build) ----------------
// pass 1: per-block LDS histogram over buckets; block reserves a contiguous chunk
__global__ __launch_bounds__(256)
void kb_hist(const int* __restrict__ col, int* __restrict__ bucket_cnt,
             int* __restrict__ blk_off) {
    __shared__ int h[256];
    int t = threadIdx.x;
    h[t] = 0;
    __syncthreads();
    int e0 = blockIdx.x * EPB;
    #pragma unroll
    for (int j = 0; j < 8; j++) {
        int e = e0 + t + j * 256;
        if (e < NE) atomicAdd(&h[col[e] >> BSHIFT], 1);
    }
    __syncthreads();
    int c = h[t];
    blk_off[blockIdx.x * 256 + t] = c ? atomicAdd(&bucket_cnt[t], c) : 0;
}

// pass 2: exclusive scan of 256 bucket counts
__global__ void kb_scan(const int* __restrict__ bucket_cnt, int* __restrict__ bucket_base) {
    __shared__ int s[256];
    int t = threadIdx.x;
    int v = bucket_cnt[t];
    s[t] = v;
    __syncthreads();
    for (int off = 1; off < 256; off <<= 1) {
        int u = (t >= off) ? s[t - off] : 0;
        __syncthreads();
        s[t] += u;
        __syncthreads();
    }
    bucket_base[t] = s[t] - v;
    if (t == 255) bucket_base[256] = s[255];
}

// pass 3: place edges into bucket-major order (block chunks per bucket are contiguous)
__global__ __launch_bounds__(256)
void kb_place(const int* __restrict__ row, const int* __restrict__ col,
              const int* __restrict__ bucket_base, const int* __restrict__ blk_off,
              int2* __restrict__ ebuf) {
    __shared__ int cur[256];
    int t = threadIdx.x;
    cur[t] = bucket_base[t] + blk_off[blockIdx.x * 256 + t];
    __syncthreads();
    int e0 = blockIdx.x * EPB;
    #pragma unroll
    for (int j = 0; j < 8; j++) {
        int e = e0 + t + j * 256;
        if (e < NE) {
            int c = col[e];
            int pos = atomicAdd(&cur[c >> BSHIFT], 1);
            ebuf[pos] = make_int2(row[e], c);
        }
    }
}

// pass 4: per bucket, scatter to final CSR slot; writes confined to ~64KB window
__global__ __launch_bounds__(256)
void kb_csr(const int2* __restrict__ ebuf, const int* __restrict__ bucket_base,
            const int* __restrict__ row_ptr, const float* __restrict__ dinv,
            int2* __restrict__ csr) {
    __shared__ int cur[512];
    int b = blockIdx.x;                      // 0..NBUCK-1
    int n0 = b << BSHIFT;
    for (int t = threadIdx.x; t < 512; t += 256) {
        int node = n0 + t;
        cur[t] = (node < NN) ? row_ptr[node] : 0;
    }
    __syncthreads();
    int s = bucket_base[b], e = bucket_base[b + 1];
    for (int p = s + threadIdx.x; p < e; p += 256) {
        int2 r = ebuf[p];
        int pos = atomicAdd(&cur[r.y - n0], 1);
        csr[pos] = make_int2(r.x, __float_as_int(dinv[r.x]));
    }
}

// ---------------- weight prep: 3x W[128x128] fp32 -> B-fragment order bf16 ----------------
__global__ void k_prepw3(const float* __restrict__ WA, const float* __restrict__ WB,
                         const float* __restrict__ WC, ushort* __restrict__ Wf) {
    int which = blockIdx.x >> 3;
    const float* W = (which == 0) ? WA : ((which == 1) ? WB : WC);
    int t = (blockIdx.x & 7) * 256 + threadIdx.x;    // 0..2047
    int lane = t & 63;
    int kt = (t >> 6) & 3;
    int nt = t >> 8;
    int quad = lane >> 4;
    int n = nt * 16 + (lane & 15);
    BF8 f;
    #pragma unroll
    for (int j = 0; j < 8; j++)
        f.us[j] = f2bf(W[(kt * 32 + quad * 8 + j) * DD + n]);
    ((uint4*)(Wf + (size_t)which * 2048 * 8))[t] = f.u4;
}

// ---------------- GEMM1: Y_bf16[N,128] = bf16(X_f32) @ Wf ----------------
__global__ __launch_bounds__(256)
void k_gemmA(const float* __restrict__ X, const ushort* __restrict__ Wf,
             ushort* __restrict__ Y) {
    int strip = blockIdx.x * 4 + (threadIdx.x >> 6);
    if (strip >= NSTRIP) return;
    int lane = threadIdx.x & 63;
    int quad = lane >> 4;
    int m = lane & 15;
    int row = strip * 16 + m;

    BF8 a[4];
    #pragma unroll
    for (int kt = 0; kt < 4; kt++) {
        const float* xp = X + (size_t)row * DD + kt * 32 + quad * 8;
        float4 v0 = *(const float4*)xp;
        float4 v1 = *(const float4*)(xp + 4);
        a[kt].us[0] = f2bf(v0.x); a[kt].us[1] = f2bf(v0.y);
        a[kt].us[2] = f2bf(v0.z); a[kt].us[3] = f2bf(v0.w);
        a[kt].us[4] = f2bf(v1.x); a[kt].us[5] = f2bf(v1.y);
        a[kt].us[6] = f2bf(v1.z); a[kt].us[7] = f2bf(v1.w);
    }

    #pragma unroll
    for (int nt = 0; nt < 8; nt++) {
        f32x4 acc = {0.f, 0.f, 0.f, 0.f};
        #pragma unroll
        for (int kt = 0; kt < 4; kt++) {
            BF8 b;
            b.u4 = ((const uint4*)Wf)[(nt * 4 + kt) * 64 + lane];
            acc = __builtin_amdgcn_mfma_f32_16x16x32_bf16(a[kt].v, b.v, acc, 0, 0, 0);
        }
        int colg = nt * 16 + m;
        #pragma unroll
        for (int r = 0; r < 4; r++)
            Y[(size_t)(strip * 16 + quad * 4 + r) * DD + colg] = f2bf(acc[r]);
    }
}

// ---------------- GEMM2: Y = bf16(relu(norm(X_bf16))) @ Wf ----------------
__global__ __launch_bounds__(256)
void k_gemmB(const uint* __restrict__ Xp, const ushort* __restrict__ Wf,
             const float* __restrict__ mul, const float* __restrict__ add,
             ushort* __restrict__ Y) {
    int strip = blockIdx.x * 4 + (threadIdx.x >> 6);
    if (strip >= NSTRIP) return;
    int lane = threadIdx.x & 63;
    int quad = lane >> 4;
    int m = lane & 15;
    int row = strip * 16 + m;

    BF8 a[4];
    #pragma unroll
    for (int kt = 0; kt < 4; kt++) {
        int f = kt * 32 + quad * 8;
        uint4 xu = *(const uint4*)(Xp + (size_t)row * 64 + kt * 16 + quad * 4);
        float4 m0 = *(const float4*)(mul + f);
        float4 m1 = *(const float4*)(mul + f + 4);
        float4 a0 = *(const float4*)(add + f);
        float4 a1 = *(const float4*)(add + f + 4);
        uint xs[4] = {xu.x, xu.y, xu.z, xu.w};
        float mm[8] = {m0.x, m0.y, m0.z, m0.w, m1.x, m1.y, m1.z, m1.w};
        float aa[8] = {a0.x, a0.y, a0.z, a0.w, a1.x, a1.y, a1.z, a1.w};
        #pragma unroll
        for (int p = 0; p < 4; p++) {
            float lo = bflo(xs[p]), hi = bfhi(xs[p]);
            a[kt].us[2 * p]     = f2bf(fmaxf(0.f, fmaf(lo, mm[2 * p],     aa[2 * p])));
            a[kt].us[2 * p + 1] = f2bf(fmaxf(0.f, fmaf(hi, mm[2 * p + 1], aa[2 * p + 1])));
        }
    }

    #pragma unroll
    for (int nt = 0; nt < 8; nt++) {
        f32x4 acc = {0.f, 0.f, 0.f, 0.f};
        #pragma unroll
        for (int kt = 0; kt < 4; kt++) {
            BF8 b;
            b.u4 = ((const uint4*)Wf)[(nt * 4 + kt) * 64 + lane];
            acc = __builtin_amdgcn_mfma_f32_16x16x32_bf16(a[kt].v, b.v, acc, 0, 0, 0);
        }
        int colg = nt * 16 + m;
        #pragma unroll
        for (int r = 0; r < 4; r++)
            Y[(size_t)(strip * 16 + quad * 4 + r) * DD + colg] = f2bf(acc[r]);
    }
}

// ---------------- aggregation (bf16 rows, scalarized edges, 4 chains) ----------------
// Y[i] = di*( sum_e h[src_e]*dinv[src_e] + h[i]*di ) + bias
__global__ __launch_bounds__(128)
void k_agg2(const uint* __restrict__ H2,
            const int* __restrict__ row_ptr, const int2* __restrict__ csr,
            const float* __restrict__ dinv,
            const float* __restrict__ bias, uint* __restrict__ Y2) {
    const int lane = threadIdx.x & 63;
    // node index is wave-uniform: force into SGPR so row_ptr/csr loads scalarize
    const int i = __builtin_amdgcn_readfirstlane(blockIdx.x * 2 + (threadIdx.x >> 6));
    const int p0 = row_ptr[i], p1 = row_ptr[i + 1];
    const float di = dinv[i];
    uint su = H2[(size_t)i * 64 + lane];
    float a0 = bflo(su) * di, a1 = bfhi(su) * di;   // self loop (x di again at end)
    float b0 = 0.f, b1 = 0.f, c0 = 0.f, c1 = 0.f, d0 = 0.f, d1 = 0.f;
    int p = p0;
    for (; p + 3 < p1; p += 4) {                    // four independent chains
        int2 e0 = csr[p];
        int2 e1 = csr[p + 1];
        int2 e2 = csr[p + 2];
        int2 e3 = csr[p + 3];
        uint h0 = H2[(size_t)e0.x * 64 + lane];
        uint h1 = H2[(size_t)e1.x * 64 + lane];
        uint h2 = H2[(size_t)e2.x * 64 + lane];
        uint h3 = H2[(size_t)e3.x * 64 + lane];
        float w0 = __int_as_float(e0.y);
        float w1 = __int_as_float(e1.y);
        float w2 = __int_as_float(e2.y);
        float w3 = __int_as_float(e3.y);
        a0 = fmaf(bflo(h0), w0, a0); a1 = fmaf(bfhi(h0), w0, a1);
        b0 = fmaf(bflo(h1), w1, b0); b1 = fmaf(bfhi(h1), w1, b1);
        c0 = fmaf(bflo(h2), w2, c0); c1 = fmaf(bfhi(h2), w2, c1);
        d0 = fmaf(bflo(h3), w3, d0); d1 = fmaf(bfhi(h3), w3, d1);
    }
    for (; p < p1; p++) {
        int2 e0 = csr[p];
        uint h0 = H2[(size_t)e0.x * 64 + lane];
        float w0 = __int_as_float(e0.y);
        a0 = fmaf(bflo(h0), w0, a0); a1 = fmaf(bfhi(h0), w0, a1);
    }
    float2 bb = *(const float2*)(bias + 2 * lane);
    float r0 = fmaf((a0 + b0) + (c0 + d0), di, bb.x);
    float r1 = fmaf((a1 + b1) + (c1 + d1), di, bb.y);
    Y2[(size_t)i * 64 + lane] = (uint)f2bf(r0) | ((uint)f2bf(r1) << 16);
}

// ---------------- GraphNorm stats over bf16 buffer ----------------
__global__ __launch_bounds__(256)
void k_stats(const uint* __restrict__ Xp, float* __restrict__ psum, float* __restrict__ psq) {
    __shared__ float shs[4][128], shq[4][128];
    int lane = threadIdx.x & 63;
    int grp = threadIdx.x >> 6;
    int r0 = blockIdx.x * RPB;
    int rend = r0 + RPB; if (rend > NN) rend = NN;
    float s0 = 0.f, s1 = 0.f, q0 = 0.f, q1 = 0.f;
    for (int r = r0 + grp; r < rend; r += 4) {
        uint u = Xp[(size_t)r * 64 + lane];
        float a = bflo(u), b = bfhi(u);
        s0 += a; q0 = fmaf(a, a, q0);
        s1 += b; q1 = fmaf(b, b, q1);
    }
    shs[grp][2 * lane] = s0; shs[grp][2 * lane + 1] = s1;
    shq[grp][2 * lane] = q0; shq[grp][2 * lane + 1] = q1;
    __syncthreads();
    if (threadIdx.x < 128) {
        int f = threadIdx.x;
        psum[blockIdx.x * DD + f] = shs[0][f] + shs[1][f] + shs[2][f] + shs[3][f];
        psq[blockIdx.x * DD + f]  = shq[0][f] + shq[1][f] + shq[2][f] + shq[3][f];
    }
}

__global__ void k_nparams(const float* __restrict__ psum, const float* __restrict__ psq,
                          const float* __restrict__ w, const float* __restrict__ b,
                          const float* __restrict__ a,
                          float* __restrict__ mul, float* __restrict__ add) {
    int f = threadIdx.x;
    float s = 0.f, q = 0.f;
    for (int j = 0; j < NSB; j++) { s += psum[j * DD + f]; q += psq[j * DD + f]; }
    const float invn = 1.0f / (float)NN;
    float m = s * invn;
    float ex2 = q * invn;
    float av = a[f];
    float var = ex2 - m * m * (2.f * av - av * av);
    float inv = rsqrtf(var + EPSV);
    mul[f] = w[f] * inv;
    add[f] = b[f] - w[f] * inv * av * m;
}

// ---------------- fused MLP head (MFMA): out = relu(T(X)@W + b0h) @ v1 + b1 ----------------
__global__ __launch_bounds__(256)
void k_mlp(const uint* __restrict__ Xp, const ushort* __restrict__ Wf,
           const float* __restrict__ mul, const float* __restrict__ add,
           const float* __restrict__ b0h, const float* __restrict__ v1,
           const float* __restrict__ b1, float* __restrict__ out) {
    int strip = blockIdx.x * 4 + (threadIdx.x >> 6);
    if (strip >= NSTRIP) return;
    int lane = threadIdx.x & 63;
    int quad = lane >> 4;
    int m = lane & 15;
    int row = strip * 16 + m;

    BF8 a[4];
    #pragma unroll
    for (int kt = 0; kt < 4; kt++) {
        int f = kt * 32 + quad * 8;
        uint4 xu = *(const uint4*)(Xp + (size_t)row * 64 + kt * 16 + quad * 4);
        float4 m0 = *(const float4*)(mul + f);
        float4 m1 = *(const float4*)(mul + f + 4);
        float4 a0 = *(const float4*)(add + f);
        float4 a1 = *(const float4*)(add + f + 4);
        uint xs[4] = {xu.x, xu.y, xu.z, xu.w};
        float mm[8] = {m0.x, m0.y, m0.z, m0.w, m1.x, m1.y, m1.z, m1.w};
        float aa[8] = {a0.x, a0.y, a0.z, a0.w, a1.x, a1.y, a1.z, a1.w};
        #pragma unroll
        for (int p = 0; p < 4; p++) {
            float lo = bflo(xs[p]), hi = bfhi(xs[p]);
            a[kt].us[2 * p]     = f2bf(fmaxf(0.f, fmaf(lo, mm[2 * p],     aa[2 * p])));
            a[kt].us[2 * p + 1] = f2bf(fmaxf(0.f, fmaf(hi, mm[2 * p + 1], aa[2 * p + 1])));
        }
    }

    float part[4] = {0.f, 0.f, 0.f, 0.f};
    #pragma unroll
    for (int nt = 0; nt < 8; nt++) {
        f32x4 acc = {0.f, 0.f, 0.f, 0.f};
        #pragma unroll
        for (int kt = 0; kt < 4; kt++) {
            BF8 b;
            b.u4 = ((const uint4*)Wf)[(nt * 4 + kt) * 64 + lane];
            acc = __builtin_amdgcn_mfma_f32_16x16x32_bf16(a[kt].v, b.v, acc, 0, 0, 0);
        }
        int colg = nt * 16 + m;
        float bb = b0h[colg];
        float vv = v1[colg];
        #pragma unroll
        for (int r = 0; r < 4; r++)
            part[r] = fmaf(fmaxf(0.f, acc[r] + bb), vv, part[r]);
    }
    #pragma unroll
    for (int r = 0; r < 4; r++) {
        #pragma unroll
        for (int off = 1; off < 16; off <<= 1)
            part[r] += __shfl_xor(part[r], off, 64);
    }
    if (m == 0) {
        float ob = b1[0];
        #pragma unroll
        for (int r = 0; r < 4; r++)
            out[strip * 16 + quad * 4 + r] = part[r] + ob;
    }
}

// ---------------- launch ----------------
static inline char* wsalloc(char*& p, size_t bytes) {
    char* r = p;
    p += (bytes + 255) & ~(size_t)255;
    return r;
}

extern "C" void kernel_launch(void* const* d_in, const int* in_sizes, int n_in,
                              void* d_out, int out_size, void* d_ws, size_t ws_size,
                              hipStream_t stream) {
    const float* x     = (const float*)d_in[0];
    const int*   ei    = (const int*)d_in[1];
    const int*   row   = ei;
    const int*   col   = ei + NE;
    const float* W0    = (const float*)d_in[2];
    const float* b0    = (const float*)d_in[3];
    const float* W1    = (const float*)d_in[4];
    const float* b1    = (const float*)d_in[5];
    const float* gn0w  = (const float*)d_in[6];
    const float* gn0b  = (const float*)d_in[7];
    const float* gn0a  = (const float*)d_in[8];
    const float* gn1w  = (const float*)d_in[9];
    const float* gn1b  = (const float*)d_in[10];
    const float* gn1a  = (const float*)d_in[11];
    const float* lin0w = (const float*)d_in[12];
    const float* lin0b = (const float*)d_in[13];
    const float* lin1w = (const float*)d_in[14];
    const float* lin1b = (const float*)d_in[15];
    float* out = (float*)d_out;

    char* p = (char*)d_ws;
    ushort* bufA   = (ushort*)wsalloc(p, (size_t)NN * DD * 2);   // bf16 h
    ushort* bufB   = (ushort*)wsalloc(p, (size_t)NN * DD * 2);   // bf16 agg out
    int2*   csr    = (int2*)  wsalloc(p, (size_t)NE * 8);        // {src, dinv[src]}
    int2*   ebuf   = (int2*)  wsalloc(p, (size_t)NE * 8);        // bucket-major {src,col}
    int*    blk_off= (int*)   wsalloc(p, (size_t)NHB * 256 * 4);
    int*    counts = (int*)   wsalloc(p, (size_t)NN * 4);
    int*    bucket_cnt = (int*)wsalloc(p, 256 * 4);              // adjacent to counts: one memset
    int*    bucket_base= (int*)wsalloc(p, 257 * 4);
    int*    row_ptr= (int*)   wsalloc(p, (size_t)(NN + 1) * 4);
    float*  dinv   = (float*) wsalloc(p, (size_t)NN * 4);
    int*    blksum = (int*)   wsalloc(p, 512 * 4);
    float*  psum   = (float*) wsalloc(p, (size_t)NSB * DD * 4);
    float*  psq    = (float*) wsalloc(p, (size_t)NSB * DD * 4);
    float*  mulv   = (float*) wsalloc(p, DD * 4);
    float*  addv   = (float*) wsalloc(p, DD * 4);
    ushort* Wf     = (ushort*)wsalloc(p, 3 * 2048 * 8 * 2);      // 3 prepped weights

    // counts (padded to 256B) and bucket_cnt are adjacent: single memset
    hipMemsetAsync(counts, 0, (((size_t)NN * 4 + 255) & ~(size_t)255) + 256 * 4, stream);

    // graph build: degrees + row_ptr + dinv
    k_count <<<(NE + 255) / 256, 256, 0, stream>>>(col, counts);
    k_scanA <<<NBLK_SCAN, 256, 0, stream>>>(counts, row_ptr, blksum, dinv);
    k_scanB <<<1, 512, 0, stream>>>(blksum);
    k_scanC <<<NBLK_SCAN, 256, 0, stream>>>(row_ptr, blksum);

    // bucketed counting sort -> CSR with L2-local writes
    kb_hist <<<NHB, 256, 0, stream>>>(col, bucket_cnt, blk_off);
    kb_scan <<<1, 256, 0, stream>>>(bucket_cnt, bucket_base);
    kb_place<<<NHB, 256, 0, stream>>>(row, col, bucket_base, blk_off, ebuf);
    kb_csr  <<<NBUCK, 256, 0, stream>>>(ebuf, bucket_base, row_ptr, dinv, csr);

    // weight prep (independent of graph build)
    k_prepw3<<<24, 256, 0, stream>>>(W0, W1, lin0w, Wf);
    ushort* Wf0 = Wf;
    ushort* Wf1 = Wf + 2048 * 8;
    ushort* Wf2 = Wf + 2 * 2048 * 8;

    const int GB = (NSTRIP + 3) / 4;   // 1563 blocks for gemm-shaped kernels

    // stage 1
    k_gemmA<<<GB, 256, 0, stream>>>(x, Wf0, bufA);
    k_agg2 <<<NN / 2, 128, 0, stream>>>((const uint*)bufA, row_ptr, csr, dinv, b0,
                                        (uint*)bufB);
    k_stats<<<NSB, 256, 0, stream>>>((const uint*)bufB, psum, psq);
    k_nparams<<<1, 128, 0, stream>>>(psum, psq, gn0w, gn0b, gn0a, mulv, addv);

    // stage 2
    k_gemmB<<<GB, 256, 0, stream>>>((const uint*)bufB, Wf1, mulv, addv, bufA);
    k_agg2 <<<NN / 2, 128, 0, stream>>>((const uint*)bufA, row_ptr, csr, dinv, b1,
                                        (uint*)bufB);
    k_stats<<<NSB, 256, 0, stream>>>((const uint*)bufB, psum, psq);
    k_nparams<<<1, 128, 0, stream>>>(psum, psq, gn1w, gn1b, gn1a, mulv, addv);

    // fused MLP head
    k_mlp<<<GB, 256, 0, stream>>>((const uint*)bufB, Wf2, mulv, addv,
                                  lin0b, lin1w, lin1b, out);

    (void)in_sizes; (void)n_in; (void)out_size; (void)ws_size;
}

// Round 5
// 429.726 us; speedup vs baseline: 2.1888x; 1.1714x over previous
//
#include <hip/hip_runtime.h>

// ---------------- problem constants ----------------
#define NN 100000      // nodes
#define NE 1600000     // edges (without self loops)
#define DD 128         // feature dim
#define EPSV 1e-5f

#define RPB 512                // rows per stats block
#define NSB 196                // ceil(NN/RPB)
#define NSTRIP 6250            // NN/16 row-strips for MFMA gemms

// bucket sort: 196 buckets of 512 nodes; 782 hist/place blocks of 2048 edges
#define BSHIFT 9
#define NBUCK 196
#define EPB 2048
#define NHB 782

typedef __attribute__((ext_vector_type(8))) __bf16 bf16x8;
typedef __attribute__((ext_vector_type(4))) float f32x4;

union BF8 {                // bit-level construction of MFMA bf16 fragments
    ushort  us[8];
    uint    ui[4];
    uint4   u4;
    bf16x8  v;
};

__device__ __forceinline__ ushort f2bf(float f) {   // RNE fp32 -> bf16 bits
    uint u = __float_as_uint(f);
    return (ushort)((u + 0x7fffu + ((u >> 16) & 1u)) >> 16);
}
__device__ __forceinline__ float bflo(uint u) { return __uint_as_float(u << 16); }
__device__ __forceinline__ float bfhi(uint u) { return __uint_as_float(u & 0xffff0000u); }

// ---------------- bucketed counting sort (write-local CSR build) ----------------
// pass 1: per-block LDS histogram over buckets; block reserves a contiguous chunk
__global__ __launch_bounds__(256)
void kb_hist(const int* __restrict__ col, int* __restrict__ bucket_cnt,
             int* __restrict__ blk_off) {
    __shared__ int h[256];
    int t = threadIdx.x;
    h[t] = 0;
    __syncthreads();
    int e0 = blockIdx.x * EPB;
    #pragma unroll
    for (int j = 0; j < 8; j++) {
        int e = e0 + t + j * 256;
        if (e < NE) atomicAdd(&h[col[e] >> BSHIFT], 1);
    }
    __syncthreads();
    int c = h[t];
    blk_off[blockIdx.x * 256 + t] = c ? atomicAdd(&bucket_cnt[t], c) : 0;
}

// pass 2: exclusive scan of 256 bucket counts
__global__ void kb_scan(const int* __restrict__ bucket_cnt, int* __restrict__ bucket_base) {
    __shared__ int s[256];
    int t = threadIdx.x;
    int v = bucket_cnt[t];
    s[t] = v;
    __syncthreads();
    for (int off = 1; off < 256; off <<= 1) {
        int u = (t >= off) ? s[t - off] : 0;
        __syncthreads();
        s[t] += u;
        __syncthreads();
    }
    bucket_base[t] = s[t] - v;
    if (t == 255) bucket_base[256] = s[255];
}

// pass 3: place edges into bucket-major order (block chunks per bucket contiguous)
__global__ __launch_bounds__(256)
void kb_place(const int* __restrict__ row, const int* __restrict__ col,
              const int* __restrict__ bucket_base, const int* __restrict__ blk_off,
              int2* __restrict__ ebuf) {
    __shared__ int cur[256];
    int t = threadIdx.x;
    cur[t] = bucket_base[t] + blk_off[blockIdx.x * 256 + t];
    __syncthreads();
    int e0 = blockIdx.x * EPB;
    #pragma unroll
    for (int j = 0; j < 8; j++) {
        int e = e0 + t + j * 256;
        if (e < NE) {
            int c = col[e];
            int pos = atomicAdd(&cur[c >> BSHIFT], 1);
            ebuf[pos] = make_int2(row[e], c);
        }
    }
}

// pass 4: per bucket -- LDS degree count, LDS scan -> row_ptr + dinv, then place.
// Replaces the old global-atomic k_count and the 3-kernel global scan entirely.
__global__ __launch_bounds__(256)
void kb_fin(const int2* __restrict__ ebuf, const int* __restrict__ bucket_base,
            int* __restrict__ row_ptr, float* __restrict__ dinv,
            int* __restrict__ csr) {
    __shared__ int deg[512];
    __shared__ int scn[256];
    int b = blockIdx.x;
    int n0 = b << BSHIFT;
    int t = threadIdx.x;
    deg[t] = 0; deg[t + 256] = 0;
    __syncthreads();
    int s = bucket_base[b], e = bucket_base[b + 1];
    for (int p = s + t; p < e; p += 256)
        atomicAdd(&deg[ebuf[p].y - n0], 1);
    __syncthreads();
    int d0 = deg[2 * t], d1 = deg[2 * t + 1];
    int pairsum = d0 + d1;
    scn[t] = pairsum;
    __syncthreads();
    for (int off = 1; off < 256; off <<= 1) {
        int u = (t >= off) ? scn[t - off] : 0;
        __syncthreads();
        scn[t] += u;
        __syncthreads();
    }
    int base = s + scn[t] - pairsum;          // global CSR offset of node n0+2t
    int node0 = n0 + 2 * t;
    if (node0 < NN)     { row_ptr[node0]     = base;      dinv[node0]     = rsqrtf((float)(d0 + 1)); }
    if (node0 + 1 < NN) { row_ptr[node0 + 1] = base + d0; dinv[node0 + 1] = rsqrtf((float)(d1 + 1)); }
    __syncthreads();                           // before reusing deg[] as cursors
    deg[2 * t] = base;
    deg[2 * t + 1] = base + d0;
    __syncthreads();
    for (int p = s + t; p < e; p += 256) {
        int2 r = ebuf[p];
        int pos = atomicAdd(&deg[r.y - n0], 1);
        csr[pos] = r.x;                        // 4B record: src only (dinv folded into rows)
    }
    if (b == 0 && t == 0) row_ptr[NN] = NE;
}

// ---------------- weight prep: 3x W[128x128] fp32 -> B-fragment order bf16 ----------------
__global__ void k_prepw3(const float* __restrict__ WA, const float* __restrict__ WB,
                         const float* __restrict__ WC, ushort* __restrict__ Wf) {
    int which = blockIdx.x >> 3;
    const float* W = (which == 0) ? WA : ((which == 1) ? WB : WC);
    int t = (blockIdx.x & 7) * 256 + threadIdx.x;    // 0..2047
    int lane = t & 63;
    int kt = (t >> 6) & 3;
    int nt = t >> 8;
    int quad = lane >> 4;
    int n = nt * 16 + (lane & 15);
    BF8 f;
    #pragma unroll
    for (int j = 0; j < 8; j++)
        f.us[j] = f2bf(W[(kt * 32 + quad * 8 + j) * DD + n]);
    ((uint4*)(Wf + (size_t)which * 2048 * 8))[t] = f.u4;
}

// ---------------- GEMM1: G_bf16[N,128] = (bf16(X_f32) @ Wf) * dinv[row] ----------------
__global__ __launch_bounds__(256)
void k_gemmA(const float* __restrict__ X, const ushort* __restrict__ Wf,
             const float* __restrict__ dinv, ushort* __restrict__ Y) {
    int strip = blockIdx.x * 4 + (threadIdx.x >> 6);
    if (strip >= NSTRIP) return;
    int lane = threadIdx.x & 63;
    int quad = lane >> 4;
    int m = lane & 15;
    int row = strip * 16 + m;

    BF8 a[4];
    #pragma unroll
    for (int kt = 0; kt < 4; kt++) {
        const float* xp = X + (size_t)row * DD + kt * 32 + quad * 8;
        float4 v0 = *(const float4*)xp;
        float4 v1 = *(const float4*)(xp + 4);
        a[kt].us[0] = f2bf(v0.x); a[kt].us[1] = f2bf(v0.y);
        a[kt].us[2] = f2bf(v0.z); a[kt].us[3] = f2bf(v0.w);
        a[kt].us[4] = f2bf(v1.x); a[kt].us[5] = f2bf(v1.y);
        a[kt].us[6] = f2bf(v1.z); a[kt].us[7] = f2bf(v1.w);
    }

    float4 dv = *(const float4*)(dinv + strip * 16 + quad * 4);
    float dvr[4] = {dv.x, dv.y, dv.z, dv.w};

    #pragma unroll
    for (int nt = 0; nt < 8; nt++) {
        f32x4 acc = {0.f, 0.f, 0.f, 0.f};
        #pragma unroll
        for (int kt = 0; kt < 4; kt++) {
            BF8 b;
            b.u4 = ((const uint4*)Wf)[(nt * 4 + kt) * 64 + lane];
            acc = __builtin_amdgcn_mfma_f32_16x16x32_bf16(a[kt].v, b.v, acc, 0, 0, 0);
        }
        int colg = nt * 16 + m;
        #pragma unroll
        for (int r = 0; r < 4; r++)
            Y[(size_t)(strip * 16 + quad * 4 + r) * DD + colg] = f2bf(acc[r] * dvr[r]);
    }
}

// ---------------- GEMM2: G = (bf16(relu(norm(X_bf16))) @ Wf) * dinv[row] ----------------
__global__ __launch_bounds__(256)
void k_gemmB(const uint* __restrict__ Xp, const ushort* __restrict__ Wf,
             const float* __restrict__ mul, const float* __restrict__ add,
             const float* __restrict__ dinv, ushort* __restrict__ Y) {
    int strip = blockIdx.x * 4 + (threadIdx.x >> 6);
    if (strip >= NSTRIP) return;
    int lane = threadIdx.x & 63;
    int quad = lane >> 4;
    int m = lane & 15;
    int row = strip * 16 + m;

    BF8 a[4];
    #pragma unroll
    for (int kt = 0; kt < 4; kt++) {
        int f = kt * 32 + quad * 8;
        uint4 xu = *(const uint4*)(Xp + (size_t)row * 64 + kt * 16 + quad * 4);
        float4 m0 = *(const float4*)(mul + f);
        float4 m1 = *(const float4*)(mul + f + 4);
        float4 a0 = *(const float4*)(add + f);
        float4 a1 = *(const float4*)(add + f + 4);
        uint xs[4] = {xu.x, xu.y, xu.z, xu.w};
        float mm[8] = {m0.x, m0.y, m0.z, m0.w, m1.x, m1.y, m1.z, m1.w};
        float aa[8] = {a0.x, a0.y, a0.z, a0.w, a1.x, a1.y, a1.z, a1.w};
        #pragma unroll
        for (int p = 0; p < 4; p++) {
            float lo = bflo(xs[p]), hi = bfhi(xs[p]);
            a[kt].us[2 * p]     = f2bf(fmaxf(0.f, fmaf(lo, mm[2 * p],     aa[2 * p])));
            a[kt].us[2 * p + 1] = f2bf(fmaxf(0.f, fmaf(hi, mm[2 * p + 1], aa[2 * p + 1])));
        }
    }

    float4 dv = *(const float4*)(dinv + strip * 16 + quad * 4);
    float dvr[4] = {dv.x, dv.y, dv.z, dv.w};

    #pragma unroll
    for (int nt = 0; nt < 8; nt++) {
        f32x4 acc = {0.f, 0.f, 0.f, 0.f};
        #pragma unroll
        for (int kt = 0; kt < 4; kt++) {
            BF8 b;
            b.u4 = ((const uint4*)Wf)[(nt * 4 + kt) * 64 + lane];
            acc = __builtin_amdgcn_mfma_f32_16x16x32_bf16(a[kt].v, b.v, acc, 0, 0, 0);
        }
        int colg = nt * 16 + m;
        #pragma unroll
        for (int r = 0; r < 4; r++)
            Y[(size_t)(strip * 16 + quad * 4 + r) * DD + colg] = f2bf(acc[r] * dvr[r]);
    }
}

// ---------------- aggregation: Y[i] = di*( sum_e g[src_e] + g[i] ) + bias ----------------
// g rows are pre-scaled by dinv in the producing GEMM; csr record = src only (4B).
__global__ __launch_bounds__(128)
void k_agg2(const uint* __restrict__ H2,
            const int* __restrict__ row_ptr, const int* __restrict__ csr,
            const float* __restrict__ dinv,
            const float* __restrict__ bias, uint* __restrict__ Y2) {
    const int lane = threadIdx.x & 63;
    // node index is wave-uniform: force into SGPR so row_ptr/csr loads scalarize
    const int i = __builtin_amdgcn_readfirstlane(blockIdx.x * 2 + (threadIdx.x >> 6));
    const int p0 = row_ptr[i], p1 = row_ptr[i + 1];
    const float di = dinv[i];
    uint su = H2[(size_t)i * 64 + lane];
    float a0 = bflo(su), a1 = bfhi(su);            // self loop term g[i]
    float b0 = 0.f, b1 = 0.f, c0 = 0.f, c1 = 0.f, d0 = 0.f, d1 = 0.f;
    int p = p0;
    for (; p + 3 < p1; p += 4) {                   // four independent chains
        int s0 = csr[p];
        int s1 = csr[p + 1];
        int s2 = csr[p + 2];
        int s3 = csr[p + 3];
        uint h0 = H2[(size_t)s0 * 64 + lane];
        uint h1 = H2[(size_t)s1 * 64 + lane];
        uint h2 = H2[(size_t)s2 * 64 + lane];
        uint h3 = H2[(size_t)s3 * 64 + lane];
        a0 += bflo(h0); a1 += bfhi(h0);
        b0 += bflo(h1); b1 += bfhi(h1);
        c0 += bflo(h2); c1 += bfhi(h2);
        d0 += bflo(h3); d1 += bfhi(h3);
    }
    for (; p < p1; p++) {
        uint h0 = H2[(size_t)csr[p] * 64 + lane];
        a0 += bflo(h0); a1 += bfhi(h0);
    }
    float2 bb = *(const float2*)(bias + 2 * lane);
    float r0 = fmaf((a0 + b0) + (c0 + d0), di, bb.x);
    float r1 = fmaf((a1 + b1) + (c1 + d1), di, bb.y);
    Y2[(size_t)i * 64 + lane] = (uint)f2bf(r0) | ((uint)f2bf(r1) << 16);
}

// ---------------- GraphNorm stats over bf16 buffer ----------------
__global__ __launch_bounds__(256)
void k_stats(const uint* __restrict__ Xp, float* __restrict__ psum, float* __restrict__ psq) {
    __shared__ float shs[4][128], shq[4][128];
    int lane = threadIdx.x & 63;
    int grp = threadIdx.x >> 6;
    int r0 = blockIdx.x * RPB;
    int rend = r0 + RPB; if (rend > NN) rend = NN;
    float s0 = 0.f, s1 = 0.f, q0 = 0.f, q1 = 0.f;
    for (int r = r0 + grp; r < rend; r += 4) {
        uint u = Xp[(size_t)r * 64 + lane];
        float a = bflo(u), b = bfhi(u);
        s0 += a; q0 = fmaf(a, a, q0);
        s1 += b; q1 = fmaf(b, b, q1);
    }
    shs[grp][2 * lane] = s0; shs[grp][2 * lane + 1] = s1;
    shq[grp][2 * lane] = q0; shq[grp][2 * lane + 1] = q1;
    __syncthreads();
    if (threadIdx.x < 128) {
        int f = threadIdx.x;
        psum[blockIdx.x * DD + f] = shs[0][f] + shs[1][f] + shs[2][f] + shs[3][f];
        psq[blockIdx.x * DD + f]  = shq[0][f] + shq[1][f] + shq[2][f] + shq[3][f];
    }
}

__global__ void k_nparams(const float* __restrict__ psum, const float* __restrict__ psq,
                          const float* __restrict__ w, const float* __restrict__ b,
                          const float* __restrict__ a,
                          float* __restrict__ mul, float* __restrict__ add) {
    int f = threadIdx.x;
    float s = 0.f, q = 0.f;
    for (int j = 0; j < NSB; j++) { s += psum[j * DD + f]; q += psq[j * DD + f]; }
    const float invn = 1.0f / (float)NN;
    float m = s * invn;
    float ex2 = q * invn;
    float av = a[f];
    float var = ex2 - m * m * (2.f * av - av * av);
    float inv = rsqrtf(var + EPSV);
    mul[f] = w[f] * inv;
    add[f] = b[f] - w[f] * inv * av * m;
}

// ---------------- fused MLP head (MFMA): out = relu(T(X)@W + b0h) @ v1 + b1 ----------------
__global__ __launch_bounds__(256)
void k_mlp(const uint* __restrict__ Xp, const ushort* __restrict__ Wf,
           const float* __restrict__ mul, const float* __restrict__ add,
           const float* __restrict__ b0h, const float* __restrict__ v1,
           const float* __restrict__ b1, float* __restrict__ out) {
    int strip = blockIdx.x * 4 + (threadIdx.x >> 6);
    if (strip >= NSTRIP) return;
    int lane = threadIdx.x & 63;
    int quad = lane >> 4;
    int m = lane & 15;
    int row = strip * 16 + m;

    BF8 a[4];
    #pragma unroll
    for (int kt = 0; kt < 4; kt++) {
        int f = kt * 32 + quad * 8;
        uint4 xu = *(const uint4*)(Xp + (size_t)row * 64 + kt * 16 + quad * 4);
        float4 m0 = *(const float4*)(mul + f);
        float4 m1 = *(const float4*)(mul + f + 4);
        float4 a0 = *(const float4*)(add + f);
        float4 a1 = *(const float4*)(add + f + 4);
        uint xs[4] = {xu.x, xu.y, xu.z, xu.w};
        float mm[8] = {m0.x, m0.y, m0.z, m0.w, m1.x, m1.y, m1.z, m1.w};
        float aa[8] = {a0.x, a0.y, a0.z, a0.w, a1.x, a1.y, a1.z, a1.w};
        #pragma unroll
        for (int p = 0; p < 4; p++) {
            float lo = bflo(xs[p]), hi = bfhi(xs[p]);
            a[kt].us[2 * p]     = f2bf(fmaxf(0.f, fmaf(lo, mm[2 * p],     aa[2 * p])));
            a[kt].us[2 * p + 1] = f2bf(fmaxf(0.f, fmaf(hi, mm[2 * p + 1], aa[2 * p + 1])));
        }
    }

    float part[4] = {0.f, 0.f, 0.f, 0.f};
    #pragma unroll
    for (int nt = 0; nt < 8; nt++) {
        f32x4 acc = {0.f, 0.f, 0.f, 0.f};
        #pragma unroll
        for (int kt = 0; kt < 4; kt++) {
            BF8 b;
            b.u4 = ((const uint4*)Wf)[(nt * 4 + kt) * 64 + lane];
            acc = __builtin_amdgcn_mfma_f32_16x16x32_bf16(a[kt].v, b.v, acc, 0, 0, 0);
        }
        int colg = nt * 16 + m;
        float bb = b0h[colg];
        float vv = v1[colg];
        #pragma unroll
        for (int r = 0; r < 4; r++)
            part[r] = fmaf(fmaxf(0.f, acc[r] + bb), vv, part[r]);
    }
    #pragma unroll
    for (int r = 0; r < 4; r++) {
        #pragma unroll
        for (int off = 1; off < 16; off <<= 1)
            part[r] += __shfl_xor(part[r], off, 64);
    }
    if (m == 0) {
        float ob = b1[0];
        #pragma unroll
        for (int r = 0; r < 4; r++)
            out[strip * 16 + quad * 4 + r] = part[r] + ob;
    }
}

// ---------------- launch ----------------
static inline char* wsalloc(char*& p, size_t bytes) {
    char* r = p;
    p += (bytes + 255) & ~(size_t)255;
    return r;
}

extern "C" void kernel_launch(void* const* d_in, const int* in_sizes, int n_in,
                              void* d_out, int out_size, void* d_ws, size_t ws_size,
                              hipStream_t stream) {
    const float* x     = (const float*)d_in[0];
    const int*   ei    = (const int*)d_in[1];
    const int*   row   = ei;
    const int*   col   = ei + NE;
    const float* W0    = (const float*)d_in[2];
    const float* b0    = (const float*)d_in[3];
    const float* W1    = (const float*)d_in[4];
    const float* b1    = (const float*)d_in[5];
    const float* gn0w  = (const float*)d_in[6];
    const float* gn0b  = (const float*)d_in[7];
    const float* gn0a  = (const float*)d_in[8];
    const float* gn1w  = (const float*)d_in[9];
    const float* gn1b  = (const float*)d_in[10];
    const float* gn1a  = (const float*)d_in[11];
    const float* lin0w = (const float*)d_in[12];
    const float* lin0b = (const float*)d_in[13];
    const float* lin1w = (const float*)d_in[14];
    const float* lin1b = (const float*)d_in[15];
    float* out = (float*)d_out;

    char* p = (char*)d_ws;
    ushort* bufA   = (ushort*)wsalloc(p, (size_t)NN * DD * 2);   // bf16 g = h*dinv
    ushort* bufB   = (ushort*)wsalloc(p, (size_t)NN * DD * 2);   // bf16 agg out
    int*    csr    = (int*)   wsalloc(p, (size_t)NE * 4);        // src only
    int2*   ebuf   = (int2*)  wsalloc(p, (size_t)NE * 8);        // bucket-major {src,col}
    int*    blk_off= (int*)   wsalloc(p, (size_t)NHB * 256 * 4);
    int*    bucket_cnt = (int*)wsalloc(p, 256 * 4);
    int*    bucket_base= (int*)wsalloc(p, 257 * 4);
    int*    row_ptr= (int*)   wsalloc(p, (size_t)(NN + 1) * 4);
    float*  dinv   = (float*) wsalloc(p, (size_t)NN * 4);
    float*  psum   = (float*) wsalloc(p, (size_t)NSB * DD * 4);
    float*  psq    = (float*) wsalloc(p, (size_t)NSB * DD * 4);
    float*  mulv   = (float*) wsalloc(p, DD * 4);
    float*  addv   = (float*) wsalloc(p, DD * 4);
    ushort* Wf     = (ushort*)wsalloc(p, 3 * 2048 * 8 * 2);      // 3 prepped weights

    hipMemsetAsync(bucket_cnt, 0, 256 * 4, stream);

    // graph build: bucketed counting sort; degrees/row_ptr/dinv derived bucket-locally
    kb_hist <<<NHB, 256, 0, stream>>>(col, bucket_cnt, blk_off);
    kb_scan <<<1, 256, 0, stream>>>(bucket_cnt, bucket_base);
    kb_place<<<NHB, 256, 0, stream>>>(row, col, bucket_base, blk_off, ebuf);
    kb_fin  <<<NBUCK, 256, 0, stream>>>(ebuf, bucket_base, row_ptr, dinv, csr);

    // weight prep
    k_prepw3<<<24, 256, 0, stream>>>(W0, W1, lin0w, Wf);
    ushort* Wf0 = Wf;
    ushort* Wf1 = Wf + 2048 * 8;
    ushort* Wf2 = Wf + 2 * 2048 * 8;

    const int GB = (NSTRIP + 3) / 4;   // 1563 blocks for gemm-shaped kernels

    // stage 1
    k_gemmA<<<GB, 256, 0, stream>>>(x, Wf0, dinv, bufA);
    k_agg2 <<<NN / 2, 128, 0, stream>>>((const uint*)bufA, row_ptr, csr, dinv, b0,
                                        (uint*)bufB);
    k_stats<<<NSB, 256, 0, stream>>>((const uint*)bufB, psum, psq);
    k_nparams<<<1, 128, 0, stream>>>(psum, psq, gn0w, gn0b, gn0a, mulv, addv);

    // stage 2
    k_gemmB<<<GB, 256, 0, stream>>>((const uint*)bufB, Wf1, mulv, addv, dinv, bufA);
    k_agg2 <<<NN / 2, 128, 0, stream>>>((const uint*)bufA, row_ptr, csr, dinv, b1,
                                        (uint*)bufB);
    k_stats<<<NSB, 256, 0, stream>>>((const uint*)bufB, psum, psq);
    k_nparams<<<1, 128, 0, stream>>>(psum, psq, gn1w, gn1b, gn1a, mulv, addv);

    // fused MLP head
    k_mlp<<<GB, 256, 0, stream>>>((const uint*)bufB, Wf2, mulv, addv,
                                  lin0b, lin1w, lin1b, out);

    (void)in_sizes; (void)n_in; (void)out_size; (void)ws_size;
}

// Round 6
// 421.298 us; speedup vs baseline: 2.2326x; 1.0200x over previous
//
#include <hip/hip_runtime.h>

// ---------------- problem constants ----------------
#define NN 100000      // nodes
#define NE 1600000     // edges (without self loops)
#define DD 128         // feature dim
#define EPSV 1e-5f

#define RPB 512                // rows per stats block
#define NSB 196                // ceil(NN/RPB)
#define NSTRIP 6250            // NN/16 row-strips for MFMA gemms

// bucket sort: 196 buckets of 512 nodes; 782 hist/place blocks of 2048 edges
#define BSHIFT 9
#define NBUCK 196
#define EPB 2048
#define NHB 782

typedef __attribute__((ext_vector_type(8))) __bf16 bf16x8;
typedef __attribute__((ext_vector_type(4))) float f32x4;

union BF8 {                // bit-level construction of MFMA bf16 fragments
    ushort  us[8];
    uint    ui[4];
    uint4   u4;
    bf16x8  v;
};

__device__ __forceinline__ ushort f2bf(float f) {   // RNE fp32 -> bf16 bits
    uint u = __float_as_uint(f);
    return (ushort)((u + 0x7fffu + ((u >> 16) & 1u)) >> 16);
}
__device__ __forceinline__ float bflo(uint u) { return __uint_as_float(u << 16); }
__device__ __forceinline__ float bfhi(uint u) { return __uint_as_float(u & 0xffff0000u); }

// ---------------- bucketed counting sort (write-local CSR build) ----------------
// pass 1: per-block LDS histogram over buckets; block reserves a contiguous chunk
__global__ __launch_bounds__(256)
void kb_hist(const int* __restrict__ col, int* __restrict__ bucket_cnt,
             int* __restrict__ blk_off) {
    __shared__ int h[256];
    int t = threadIdx.x;
    h[t] = 0;
    __syncthreads();
    int e0 = blockIdx.x * EPB;
    #pragma unroll
    for (int j = 0; j < 8; j++) {
        int e = e0 + t + j * 256;
        if (e < NE) atomicAdd(&h[col[e] >> BSHIFT], 1);
    }
    __syncthreads();
    int c = h[t];
    blk_off[blockIdx.x * 256 + t] = c ? atomicAdd(&bucket_cnt[t], c) : 0;
}

// pass 2: exclusive scan of 256 bucket counts
__global__ void kb_scan(const int* __restrict__ bucket_cnt, int* __restrict__ bucket_base) {
    __shared__ int s[256];
    int t = threadIdx.x;
    int v = bucket_cnt[t];
    s[t] = v;
    __syncthreads();
    for (int off = 1; off < 256; off <<= 1) {
        int u = (t >= off) ? s[t - off] : 0;
        __syncthreads();
        s[t] += u;
        __syncthreads();
    }
    bucket_base[t] = s[t] - v;
    if (t == 255) bucket_base[256] = s[255];
}

// pass 3: place edges into bucket-major order, packed 4B: (src<<9)|local_col
__global__ __launch_bounds__(256)
void kb_place(const int* __restrict__ row, const int* __restrict__ col,
              const int* __restrict__ bucket_base, const int* __restrict__ blk_off,
              uint* __restrict__ ebuf) {
    __shared__ int cur[256];
    int t = threadIdx.x;
    cur[t] = bucket_base[t] + blk_off[blockIdx.x * 256 + t];
    __syncthreads();
    int e0 = blockIdx.x * EPB;
    #pragma unroll
    for (int j = 0; j < 8; j++) {
        int e = e0 + t + j * 256;
        if (e < NE) {
            int c = col[e];
            int pos = atomicAdd(&cur[c >> BSHIFT], 1);
            ebuf[pos] = ((uint)row[e] << BSHIFT) | (uint)(c & ((1 << BSHIFT) - 1));
        }
    }
}

// pass 4: per bucket -- LDS degree count, LDS scan -> row_ptr + dinv, then place.
__global__ __launch_bounds__(256)
void kb_fin(const uint* __restrict__ ebuf, const int* __restrict__ bucket_base,
            int* __restrict__ row_ptr, float* __restrict__ dinv,
            int* __restrict__ csr) {
    __shared__ int deg[512];
    __shared__ int scn[256];
    int b = blockIdx.x;
    int n0 = b << BSHIFT;
    int t = threadIdx.x;
    deg[t] = 0; deg[t + 256] = 0;
    __syncthreads();
    int s = bucket_base[b], e = bucket_base[b + 1];
    for (int p = s + t; p < e; p += 256)
        atomicAdd(&deg[ebuf[p] & 511u], 1);
    __syncthreads();
    int d0 = deg[2 * t], d1 = deg[2 * t + 1];
    int pairsum = d0 + d1;
    scn[t] = pairsum;
    __syncthreads();
    for (int off = 1; off < 256; off <<= 1) {
        int u = (t >= off) ? scn[t - off] : 0;
        __syncthreads();
        scn[t] += u;
        __syncthreads();
    }
    int base = s + scn[t] - pairsum;          // global CSR offset of node n0+2t
    int node0 = n0 + 2 * t;
    if (node0 < NN)     { row_ptr[node0]     = base;      dinv[node0]     = rsqrtf((float)(d0 + 1)); }
    if (node0 + 1 < NN) { row_ptr[node0 + 1] = base + d0; dinv[node0 + 1] = rsqrtf((float)(d1 + 1)); }
    __syncthreads();                           // before reusing deg[] as cursors
    deg[2 * t] = base;
    deg[2 * t + 1] = base + d0;
    __syncthreads();
    for (int p = s + t; p < e; p += 256) {
        uint r = ebuf[p];
        int pos = atomicAdd(&deg[r & 511u], 1);
        csr[pos] = (int)(r >> BSHIFT);         // 4B record: src only
    }
    if (b == 0 && t == 0) row_ptr[NN] = NE;
}

// ---------------- weight prep: 3x W[128x128] fp32 -> B-fragment order bf16 ----------------
__global__ void k_prepw3(const float* __restrict__ WA, const float* __restrict__ WB,
                         const float* __restrict__ WC, ushort* __restrict__ Wf) {
    int which = blockIdx.x >> 3;
    const float* W = (which == 0) ? WA : ((which == 1) ? WB : WC);
    int t = (blockIdx.x & 7) * 256 + threadIdx.x;    // 0..2047
    int lane = t & 63;
    int kt = (t >> 6) & 3;
    int nt = t >> 8;
    int quad = lane >> 4;
    int n = nt * 16 + (lane & 15);
    BF8 f;
    #pragma unroll
    for (int j = 0; j < 8; j++)
        f.us[j] = f2bf(W[(kt * 32 + quad * 8 + j) * DD + n]);
    ((uint4*)(Wf + (size_t)which * 2048 * 8))[t] = f.u4;
}

// ---------------- GEMM1: G_bf16[N,128] = (bf16(X_f32) @ Wf) * dinv[row] ----------------
__global__ __launch_bounds__(256)
void k_gemmA(const float* __restrict__ X, const ushort* __restrict__ Wf,
             const float* __restrict__ dinv, ushort* __restrict__ Y) {
    int strip = blockIdx.x * 4 + (threadIdx.x >> 6);
    if (strip >= NSTRIP) return;
    int lane = threadIdx.x & 63;
    int quad = lane >> 4;
    int m = lane & 15;
    int row = strip * 16 + m;

    BF8 a[4];
    #pragma unroll
    for (int kt = 0; kt < 4; kt++) {
        const float* xp = X + (size_t)row * DD + kt * 32 + quad * 8;
        float4 v0 = *(const float4*)xp;
        float4 v1 = *(const float4*)(xp + 4);
        a[kt].us[0] = f2bf(v0.x); a[kt].us[1] = f2bf(v0.y);
        a[kt].us[2] = f2bf(v0.z); a[kt].us[3] = f2bf(v0.w);
        a[kt].us[4] = f2bf(v1.x); a[kt].us[5] = f2bf(v1.y);
        a[kt].us[6] = f2bf(v1.z); a[kt].us[7] = f2bf(v1.w);
    }

    float4 dv = *(const float4*)(dinv + strip * 16 + quad * 4);
    float dvr[4] = {dv.x, dv.y, dv.z, dv.w};

    #pragma unroll
    for (int nt = 0; nt < 8; nt++) {
        f32x4 acc = {0.f, 0.f, 0.f, 0.f};
        #pragma unroll
        for (int kt = 0; kt < 4; kt++) {
            BF8 b;
            b.u4 = ((const uint4*)Wf)[(nt * 4 + kt) * 64 + lane];
            acc = __builtin_amdgcn_mfma_f32_16x16x32_bf16(a[kt].v, b.v, acc, 0, 0, 0);
        }
        int colg = nt * 16 + m;
        #pragma unroll
        for (int r = 0; r < 4; r++)
            Y[(size_t)(strip * 16 + quad * 4 + r) * DD + colg] = f2bf(acc[r] * dvr[r]);
    }
}

// ---------------- GEMM2: G = (bf16(relu(norm(X_bf16))) @ Wf) * dinv[row] ----------------
__global__ __launch_bounds__(256)
void k_gemmB(const uint* __restrict__ Xp, const ushort* __restrict__ Wf,
             const float* __restrict__ mul, const float* __restrict__ add,
             const float* __restrict__ dinv, ushort* __restrict__ Y) {
    int strip = blockIdx.x * 4 + (threadIdx.x >> 6);
    if (strip >= NSTRIP) return;
    int lane = threadIdx.x & 63;
    int quad = lane >> 4;
    int m = lane & 15;
    int row = strip * 16 + m;

    BF8 a[4];
    #pragma unroll
    for (int kt = 0; kt < 4; kt++) {
        int f = kt * 32 + quad * 8;
        uint4 xu = *(const uint4*)(Xp + (size_t)row * 64 + kt * 16 + quad * 4);
        float4 m0 = *(const float4*)(mul + f);
        float4 m1 = *(const float4*)(mul + f + 4);
        float4 a0 = *(const float4*)(add + f);
        float4 a1 = *(const float4*)(add + f + 4);
        uint xs[4] = {xu.x, xu.y, xu.z, xu.w};
        float mm[8] = {m0.x, m0.y, m0.z, m0.w, m1.x, m1.y, m1.z, m1.w};
        float aa[8] = {a0.x, a0.y, a0.z, a0.w, a1.x, a1.y, a1.z, a1.w};
        #pragma unroll
        for (int p = 0; p < 4; p++) {
            float lo = bflo(xs[p]), hi = bfhi(xs[p]);
            a[kt].us[2 * p]     = f2bf(fmaxf(0.f, fmaf(lo, mm[2 * p],     aa[2 * p])));
            a[kt].us[2 * p + 1] = f2bf(fmaxf(0.f, fmaf(hi, mm[2 * p + 1], aa[2 * p + 1])));
        }
    }

    float4 dv = *(const float4*)(dinv + strip * 16 + quad * 4);
    float dvr[4] = {dv.x, dv.y, dv.z, dv.w};

    #pragma unroll
    for (int nt = 0; nt < 8; nt++) {
        f32x4 acc = {0.f, 0.f, 0.f, 0.f};
        #pragma unroll
        for (int kt = 0; kt < 4; kt++) {
            BF8 b;
            b.u4 = ((const uint4*)Wf)[(nt * 4 + kt) * 64 + lane];
            acc = __builtin_amdgcn_mfma_f32_16x16x32_bf16(a[kt].v, b.v, acc, 0, 0, 0);
        }
        int colg = nt * 16 + m;
        #pragma unroll
        for (int r = 0; r < 4; r++)
            Y[(size_t)(strip * 16 + quad * 4 + r) * DD + colg] = f2bf(acc[r] * dvr[r]);
    }
}

// ---------------- aggregation: Y[i] = di*( sum_e g[src_e] + g[i] ) + bias ----------------
// 256 threads = 4 waves = 4 nodes; 8 gathers in flight per wave.
__global__ __launch_bounds__(256)
void k_agg2(const uint* __restrict__ H2,
            const int* __restrict__ row_ptr, const int* __restrict__ csr,
            const float* __restrict__ dinv,
            const float* __restrict__ bias, uint* __restrict__ Y2) {
    const int lane = threadIdx.x & 63;
    // node index is wave-uniform: force into SGPR so row_ptr/csr loads scalarize
    const int i = __builtin_amdgcn_readfirstlane(blockIdx.x * 4 + (threadIdx.x >> 6));
    const int p0 = row_ptr[i], p1 = row_ptr[i + 1];
    const float di = dinv[i];
    uint su = H2[(size_t)i * 64 + lane];
    float a0 = bflo(su), a1 = bfhi(su);            // self loop term g[i]
    float b0 = 0.f, b1 = 0.f, c0 = 0.f, c1 = 0.f, d0 = 0.f, d1 = 0.f;
    int p = p0;
    for (; p + 7 < p1; p += 8) {                   // 8 loads in flight
        int s0 = csr[p],     s1 = csr[p + 1], s2 = csr[p + 2], s3 = csr[p + 3];
        int s4 = csr[p + 4], s5 = csr[p + 5], s6 = csr[p + 6], s7 = csr[p + 7];
        uint h0 = H2[(size_t)s0 * 64 + lane];
        uint h1 = H2[(size_t)s1 * 64 + lane];
        uint h2 = H2[(size_t)s2 * 64 + lane];
        uint h3 = H2[(size_t)s3 * 64 + lane];
        uint h4 = H2[(size_t)s4 * 64 + lane];
        uint h5 = H2[(size_t)s5 * 64 + lane];
        uint h6 = H2[(size_t)s6 * 64 + lane];
        uint h7 = H2[(size_t)s7 * 64 + lane];
        a0 += bflo(h0); a1 += bfhi(h0);
        b0 += bflo(h1); b1 += bfhi(h1);
        c0 += bflo(h2); c1 += bfhi(h2);
        d0 += bflo(h3); d1 += bfhi(h3);
        a0 += bflo(h4); a1 += bfhi(h4);
        b0 += bflo(h5); b1 += bfhi(h5);
        c0 += bflo(h6); c1 += bfhi(h6);
        d0 += bflo(h7); d1 += bfhi(h7);
    }
    for (; p + 3 < p1; p += 4) {
        int s0 = csr[p], s1 = csr[p + 1], s2 = csr[p + 2], s3 = csr[p + 3];
        uint h0 = H2[(size_t)s0 * 64 + lane];
        uint h1 = H2[(size_t)s1 * 64 + lane];
        uint h2 = H2[(size_t)s2 * 64 + lane];
        uint h3 = H2[(size_t)s3 * 64 + lane];
        a0 += bflo(h0); a1 += bfhi(h0);
        b0 += bflo(h1); b1 += bfhi(h1);
        c0 += bflo(h2); c1 += bfhi(h2);
        d0 += bflo(h3); d1 += bfhi(h3);
    }
    for (; p < p1; p++) {
        uint h0 = H2[(size_t)csr[p] * 64 + lane];
        a0 += bflo(h0); a1 += bfhi(h0);
    }
    float2 bb = *(const float2*)(bias + 2 * lane);
    float r0 = fmaf((a0 + b0) + (c0 + d0), di, bb.x);
    float r1 = fmaf((a1 + b1) + (c1 + d1), di, bb.y);
    Y2[(size_t)i * 64 + lane] = (uint)f2bf(r0) | ((uint)f2bf(r1) << 16);
}

// ---------------- GraphNorm stats over bf16 buffer ----------------
__global__ __launch_bounds__(256)
void k_stats(const uint* __restrict__ Xp, float* __restrict__ psum, float* __restrict__ psq) {
    __shared__ float shs[4][128], shq[4][128];
    int lane = threadIdx.x & 63;
    int grp = threadIdx.x >> 6;
    int r0 = blockIdx.x * RPB;
    int rend = r0 + RPB; if (rend > NN) rend = NN;
    float s0 = 0.f, s1 = 0.f, q0 = 0.f, q1 = 0.f;
    for (int r = r0 + grp; r < rend; r += 4) {
        uint u = Xp[(size_t)r * 64 + lane];
        float a = bflo(u), b = bfhi(u);
        s0 += a; q0 = fmaf(a, a, q0);
        s1 += b; q1 = fmaf(b, b, q1);
    }
    shs[grp][2 * lane] = s0; shs[grp][2 * lane + 1] = s1;
    shq[grp][2 * lane] = q0; shq[grp][2 * lane + 1] = q1;
    __syncthreads();
    if (threadIdx.x < 128) {
        int f = threadIdx.x;
        psum[blockIdx.x * DD + f] = shs[0][f] + shs[1][f] + shs[2][f] + shs[3][f];
        psq[blockIdx.x * DD + f]  = shq[0][f] + shq[1][f] + shq[2][f] + shq[3][f];
    }
}

__global__ void k_nparams(const float* __restrict__ psum, const float* __restrict__ psq,
                          const float* __restrict__ w, const float* __restrict__ b,
                          const float* __restrict__ a,
                          float* __restrict__ mul, float* __restrict__ add) {
    int f = threadIdx.x;
    float s = 0.f, q = 0.f;
    for (int j = 0; j < NSB; j++) { s += psum[j * DD + f]; q += psq[j * DD + f]; }
    const float invn = 1.0f / (float)NN;
    float m = s * invn;
    float ex2 = q * invn;
    float av = a[f];
    float var = ex2 - m * m * (2.f * av - av * av);
    float inv = rsqrtf(var + EPSV);
    mul[f] = w[f] * inv;
    add[f] = b[f] - w[f] * inv * av * m;
}

// ---------------- fused MLP head (MFMA): out = relu(T(X)@W + b0h) @ v1 + b1 ----------------
__global__ __launch_bounds__(256)
void k_mlp(const uint* __restrict__ Xp, const ushort* __restrict__ Wf,
           const float* __restrict__ mul, const float* __restrict__ add,
           const float* __restrict__ b0h, const float* __restrict__ v1,
           const float* __restrict__ b1, float* __restrict__ out) {
    int strip = blockIdx.x * 4 + (threadIdx.x >> 6);
    if (strip >= NSTRIP) return;
    int lane = threadIdx.x & 63;
    int quad = lane >> 4;
    int m = lane & 15;
    int row = strip * 16 + m;

    BF8 a[4];
    #pragma unroll
    for (int kt = 0; kt < 4; kt++) {
        int f = kt * 32 + quad * 8;
        uint4 xu = *(const uint4*)(Xp + (size_t)row * 64 + kt * 16 + quad * 4);
        float4 m0 = *(const float4*)(mul + f);
        float4 m1 = *(const float4*)(mul + f + 4);
        float4 a0 = *(const float4*)(add + f);
        float4 a1 = *(const float4*)(add + f + 4);
        uint xs[4] = {xu.x, xu.y, xu.z, xu.w};
        float mm[8] = {m0.x, m0.y, m0.z, m0.w, m1.x, m1.y, m1.z, m1.w};
        float aa[8] = {a0.x, a0.y, a0.z, a0.w, a1.x, a1.y, a1.z, a1.w};
        #pragma unroll
        for (int p = 0; p < 4; p++) {
            float lo = bflo(xs[p]), hi = bfhi(xs[p]);
            a[kt].us[2 * p]     = f2bf(fmaxf(0.f, fmaf(lo, mm[2 * p],     aa[2 * p])));
            a[kt].us[2 * p + 1] = f2bf(fmaxf(0.f, fmaf(hi, mm[2 * p + 1], aa[2 * p + 1])));
        }
    }

    float part[4] = {0.f, 0.f, 0.f, 0.f};
    #pragma unroll
    for (int nt = 0; nt < 8; nt++) {
        f32x4 acc = {0.f, 0.f, 0.f, 0.f};
        #pragma unroll
        for (int kt = 0; kt < 4; kt++) {
            BF8 b;
            b.u4 = ((const uint4*)Wf)[(nt * 4 + kt) * 64 + lane];
            acc = __builtin_amdgcn_mfma_f32_16x16x32_bf16(a[kt].v, b.v, acc, 0, 0, 0);
        }
        int colg = nt * 16 + m;
        float bb = b0h[colg];
        float vv = v1[colg];
        #pragma unroll
        for (int r = 0; r < 4; r++)
            part[r] = fmaf(fmaxf(0.f, acc[r] + bb), vv, part[r]);
    }
    #pragma unroll
    for (int r = 0; r < 4; r++) {
        #pragma unroll
        for (int off = 1; off < 16; off <<= 1)
            part[r] += __shfl_xor(part[r], off, 64);
    }
    if (m == 0) {
        float ob = b1[0];
        #pragma unroll
        for (int r = 0; r < 4; r++)
            out[strip * 16 + quad * 4 + r] = part[r] + ob;
    }
}

// ---------------- launch ----------------
static inline char* wsalloc(char*& p, size_t bytes) {
    char* r = p;
    p += (bytes + 255) & ~(size_t)255;
    return r;
}

extern "C" void kernel_launch(void* const* d_in, const int* in_sizes, int n_in,
                              void* d_out, int out_size, void* d_ws, size_t ws_size,
                              hipStream_t stream) {
    const float* x     = (const float*)d_in[0];
    const int*   ei    = (const int*)d_in[1];
    const int*   row   = ei;
    const int*   col   = ei + NE;
    const float* W0    = (const float*)d_in[2];
    const float* b0    = (const float*)d_in[3];
    const float* W1    = (const float*)d_in[4];
    const float* b1    = (const float*)d_in[5];
    const float* gn0w  = (const float*)d_in[6];
    const float* gn0b  = (const float*)d_in[7];
    const float* gn0a  = (const float*)d_in[8];
    const float* gn1w  = (const float*)d_in[9];
    const float* gn1b  = (const float*)d_in[10];
    const float* gn1a  = (const float*)d_in[11];
    const float* lin0w = (const float*)d_in[12];
    const float* lin0b = (const float*)d_in[13];
    const float* lin1w = (const float*)d_in[14];
    const float* lin1b = (const float*)d_in[15];
    float* out = (float*)d_out;

    char* p = (char*)d_ws;
    ushort* bufA   = (ushort*)wsalloc(p, (size_t)NN * DD * 2);   // bf16 g = h*dinv
    ushort* bufB   = (ushort*)wsalloc(p, (size_t)NN * DD * 2);   // bf16 agg out
    int*    csr    = (int*)   wsalloc(p, (size_t)NE * 4);        // src only
    uint*   ebuf   = (uint*)  wsalloc(p, (size_t)NE * 4);        // packed (src<<9)|local
    int*    blk_off= (int*)   wsalloc(p, (size_t)NHB * 256 * 4);
    int*    bucket_cnt = (int*)wsalloc(p, 256 * 4);
    int*    bucket_base= (int*)wsalloc(p, 257 * 4);
    int*    row_ptr= (int*)   wsalloc(p, (size_t)(NN + 1) * 4);
    float*  dinv   = (float*) wsalloc(p, (size_t)NN * 4);
    float*  psum   = (float*) wsalloc(p, (size_t)NSB * DD * 4);
    float*  psq    = (float*) wsalloc(p, (size_t)NSB * DD * 4);
    float*  mulv   = (float*) wsalloc(p, DD * 4);
    float*  addv   = (float*) wsalloc(p, DD * 4);
    ushort* Wf     = (ushort*)wsalloc(p, 3 * 2048 * 8 * 2);      // 3 prepped weights

    hipMemsetAsync(bucket_cnt, 0, 256 * 4, stream);

    // graph build: bucketed counting sort; degrees/row_ptr/dinv derived bucket-locally
    kb_hist <<<NHB, 256, 0, stream>>>(col, bucket_cnt, blk_off);
    kb_scan <<<1, 256, 0, stream>>>(bucket_cnt, bucket_base);
    kb_place<<<NHB, 256, 0, stream>>>(row, col, bucket_base, blk_off, ebuf);
    kb_fin  <<<NBUCK, 256, 0, stream>>>(ebuf, bucket_base, row_ptr, dinv, csr);

    // weight prep
    k_prepw3<<<24, 256, 0, stream>>>(W0, W1, lin0w, Wf);
    ushort* Wf0 = Wf;
    ushort* Wf1 = Wf + 2048 * 8;
    ushort* Wf2 = Wf + 2 * 2048 * 8;

    const int GB = (NSTRIP + 3) / 4;   // 1563 blocks for gemm-shaped kernels

    // stage 1
    k_gemmA<<<GB, 256, 0, stream>>>(x, Wf0, dinv, bufA);
    k_agg2 <<<NN / 4, 256, 0, stream>>>((const uint*)bufA, row_ptr, csr, dinv, b0,
                                        (uint*)bufB);
    k_stats<<<NSB, 256, 0, stream>>>((const uint*)bufB, psum, psq);
    k_nparams<<<1, 128, 0, stream>>>(psum, psq, gn0w, gn0b, gn0a, mulv, addv);

    // stage 2
    k_gemmB<<<GB, 256, 0, stream>>>((const uint*)bufB, Wf1, mulv, addv, dinv, bufA);
    k_agg2 <<<NN / 4, 256, 0, stream>>>((const uint*)bufA, row_ptr, csr, dinv, b1,
                                        (uint*)bufB);
    k_stats<<<NSB, 256, 0, stream>>>((const uint*)bufB, psum, psq);
    k_nparams<<<1, 128, 0, stream>>>(psum, psq, gn1w, gn1b, gn1a, mulv, addv);

    // fused MLP head
    k_mlp<<<GB, 256, 0, stream>>>((const uint*)bufB, Wf2, mulv, addv,
                                  lin0b, lin1w, lin1b, out);

    (void)in_sizes; (void)n_in; (void)out_size; (void)ws_size;
}